// Round 2
// baseline (2240.351 us; speedup 1.0000x reference)
//
#include <hip/hip_runtime.h>

// GraphTransformerModel: 2-layer graph attention network.
// CSR build -> in-GEMM -> qkv0/res0 GEMMs -> attn0 (per-dst wave) -> gres0+LN
// -> per-2-head passes {qkv slice GEMMs -> attn1 accumulate} -> res1 -> gres1.
// q/k/v in bf16; all accumulation f32. Peak workspace ~186 MB (reuse + splits).

typedef unsigned short u16;

__device__ __forceinline__ float bf2f(unsigned short u) {
    return __uint_as_float(((unsigned)u) << 16);
}
__device__ __forceinline__ unsigned short f2bf(float f) {
    unsigned u = __float_as_uint(f);
    unsigned r = 0x7fffu + ((u >> 16) & 1u);   // round-to-nearest-even
    return (unsigned short)((u + r) >> 16);
}

// ---------------- generic f32 GEMM: C[M,N] = A[M,K] @ B[K,N] + bias ----------------
// 256 threads, 64x64 tile, 4x4 per-thread, BK=16. B row stride = ldb, C row stride = ldc.
template <bool OUTBF16>
__global__ __launch_bounds__(256) void gemm_k(const float* __restrict__ A,
                                              const float* __restrict__ B,
                                              const float* __restrict__ bias,
                                              void* __restrict__ C,
                                              int M, int N, int K, int ldb, int ldc) {
    __shared__ float As[16][68];  // [k][m], padded
    __shared__ float Bs[16][68];  // [k][n], padded
    const int bm = blockIdx.y * 64;
    const int bn = blockIdx.x * 64;
    const int t = threadIdx.x;
    const int tx = t & 15, ty = t >> 4;
    float acc[4][4] = {};
    for (int k0 = 0; k0 < K; k0 += 16) {
        {   // stage A tile (64 rows x 16 k)
            int r = t >> 2, kk = (t & 3) << 2;
            int gr = bm + r;
            float4 av = make_float4(0.f, 0.f, 0.f, 0.f);
            if (gr < M) av = *(const float4*)(A + (size_t)gr * K + (k0 + kk));
            As[kk + 0][r] = av.x; As[kk + 1][r] = av.y;
            As[kk + 2][r] = av.z; As[kk + 3][r] = av.w;
        }
        {   // stage B tile (16 k x 64 n)
            int kk = t >> 4, c = (t & 15) << 2;
            *(float4*)(&Bs[kk][c]) = *(const float4*)(B + (size_t)(k0 + kk) * ldb + (bn + c));
        }
        __syncthreads();
#pragma unroll
        for (int kk = 0; kk < 16; ++kk) {
            float a[4], b[4];
            *(float4*)a = *(const float4*)(&As[kk][ty << 2]);
            *(float4*)b = *(const float4*)(&Bs[kk][tx << 2]);
#pragma unroll
            for (int i = 0; i < 4; ++i)
#pragma unroll
                for (int j = 0; j < 4; ++j) acc[i][j] = fmaf(a[i], b[j], acc[i][j]);
        }
        __syncthreads();
    }
#pragma unroll
    for (int i = 0; i < 4; ++i) {
        int row = bm + (ty << 2) + i;
        if (row >= M) continue;
#pragma unroll
        for (int j = 0; j < 4; ++j) {
            int col = bn + (tx << 2) + j;
            if (col >= N) continue;
            float v = acc[i][j] + bias[col];
            if (OUTBF16) ((u16*)C)[(size_t)row * ldc + col] = f2bf(v);
            else         ((float*)C)[(size_t)row * ldc + col] = v;
        }
    }
}

// ---------------- CSR build ----------------
__global__ void zero2_k(int* __restrict__ a, int* __restrict__ b, int n) {
    int i = blockIdx.x * 256 + threadIdx.x;
    if (i < n) { a[i] = 0; b[i] = 0; }
}

__global__ void hist_k(const int* __restrict__ dst, int* __restrict__ cnt, int E) {
    int i = blockIdx.x * 256 + threadIdx.x;
    if (i < E) atomicAdd(&cnt[dst[i]], 1);
}

__global__ void blocksum_k(const int* __restrict__ cnt, int* __restrict__ bsum, int n) {
    __shared__ int sd[256];
    int i = blockIdx.x * 256 + threadIdx.x;
    sd[threadIdx.x] = (i < n) ? cnt[i] : 0;
    __syncthreads();
    for (int off = 128; off > 0; off >>= 1) {
        if (threadIdx.x < off) sd[threadIdx.x] += sd[threadIdx.x + off];
        __syncthreads();
    }
    if (threadIdx.x == 0) bsum[blockIdx.x] = sd[0];
}

__global__ void scanb_k(int* bsum, int nb) {  // exclusive scan of <=512 block sums
    __shared__ int tmp[512];
    int t = threadIdx.x;
    tmp[t] = (t < nb) ? bsum[t] : 0;
    __syncthreads();
    for (int off = 1; off < 512; off <<= 1) {
        int v = (t >= off) ? tmp[t - off] : 0;
        __syncthreads();
        tmp[t] += v;
        __syncthreads();
    }
    if (t < nb) bsum[t] = (t ? tmp[t - 1] : 0);
}

__global__ void scanc_k(const int* __restrict__ cnt, const int* __restrict__ bsum,
                        int* __restrict__ row_off, int n, int E) {
    __shared__ int tmp[256];
    int b = blockIdx.x, t = threadIdx.x;
    int i = b * 256 + t;
    int own = (i < n) ? cnt[i] : 0;
    tmp[t] = own;
    __syncthreads();
    for (int off = 1; off < 256; off <<= 1) {
        int v = (t >= off) ? tmp[t - off] : 0;
        __syncthreads();
        tmp[t] += v;
        __syncthreads();
    }
    if (i < n) row_off[i] = bsum[b] + tmp[t] - own;
    if (b == 0 && t == 0) row_off[n] = E;
}

__global__ void scatter_k(const int* __restrict__ src, const int* __restrict__ dst,
                          const int* __restrict__ row_off, int* __restrict__ cur,
                          int* __restrict__ csr_src, int E) {
    int i = blockIdx.x * 256 + threadIdx.x;
    if (i < E) {
        int d = dst[i];
        int pos = row_off[d] + atomicAdd(&cur[d], 1);
        csr_src[pos] = src[i];
    }
}

// ---------------- attention layer 0: 8 heads x d=16, F=128, concat ----------------
// one wave/node; lane l holds feats 2l,2l+1 (head l>>3); dot reduce over 8-lane groups.
__global__ __launch_bounds__(256) void attn0_k(const u16* __restrict__ q, const u16* __restrict__ k,
                                               const u16* __restrict__ v,
                                               const int* __restrict__ row_off,
                                               const int* __restrict__ csr,
                                               float* __restrict__ out, int n) {
    int w = (blockIdx.x * 256 + threadIdx.x) >> 6;
    int lane = threadIdx.x & 63;
    if (w >= n) return;
    int beg = row_off[w], end = row_off[w + 1];
    unsigned kv = *(const unsigned*)(k + (size_t)w * 128 + 2 * lane);
    float k0f = bf2f((u16)kv), k1f = bf2f((u16)(kv >> 16));
    float den = 0.f, num0 = 0.f, num1 = 0.f;
    for (int e = beg; e < end; ++e) {
        int s = csr[e];
        unsigned qv = *(const unsigned*)(q + (size_t)s * 128 + 2 * lane);
        float p = bf2f((u16)qv) * k0f + bf2f((u16)(qv >> 16)) * k1f;
        p += __shfl_xor(p, 1);
        p += __shfl_xor(p, 2);
        p += __shfl_xor(p, 4);
        float wt = __expf(p * 0.25f);   // 1/sqrt(16)
        den += wt;
        unsigned vv = *(const unsigned*)(v + (size_t)s * 128 + 2 * lane);
        num0 = fmaf(wt, bf2f((u16)vv), num0);
        num1 = fmaf(wt, bf2f((u16)(vv >> 16)), num1);
    }
    float inv = (end > beg) ? 1.f / den : 0.f;
    *(float2*)(out + (size_t)w * 128 + 2 * lane) = make_float2(num0 * inv, num1 * inv);
}

// ---------------- attention layer 1 (one 2-head pass): d=64, accumulate mean ----------------
// lane l holds feats 2l,2l+1 of the pass slice (head l>>5); dot reduce over 32-lane groups.
template <bool FIRST>
__global__ __launch_bounds__(256) void attn1_k(const u16* __restrict__ q, const u16* __restrict__ k,
                                               const u16* __restrict__ v,
                                               const int* __restrict__ row_off,
                                               const int* __restrict__ csr,
                                               float* __restrict__ out, int n) {
    int w = (blockIdx.x * 256 + threadIdx.x) >> 6;
    int lane = threadIdx.x & 63;
    if (w >= n) return;
    int beg = row_off[w], end = row_off[w + 1];
    unsigned kv = *(const unsigned*)(k + (size_t)w * 128 + 2 * lane);
    float k0f = bf2f((u16)kv), k1f = bf2f((u16)(kv >> 16));
    float den = 0.f, num0 = 0.f, num1 = 0.f;
    for (int e = beg; e < end; ++e) {
        int s = csr[e];
        unsigned qv = *(const unsigned*)(q + (size_t)s * 128 + 2 * lane);
        float p = bf2f((u16)qv) * k0f + bf2f((u16)(qv >> 16)) * k1f;
        p += __shfl_xor(p, 1);
        p += __shfl_xor(p, 2);
        p += __shfl_xor(p, 4);
        p += __shfl_xor(p, 8);
        p += __shfl_xor(p, 16);
        float wt = __expf(p * 0.125f);   // 1/sqrt(64)
        den += wt;
        unsigned vv = *(const unsigned*)(v + (size_t)s * 128 + 2 * lane);
        num0 = fmaf(wt, bf2f((u16)vv), num0);
        num1 = fmaf(wt, bf2f((u16)(vv >> 16)), num1);
    }
    float inv = (end > beg) ? 1.f / den : 0.f;
    float o0 = num0 * inv, o1 = num1 * inv;
    o0 += __shfl_xor(o0, 32);   // combine the two heads (same output dim)
    o1 += __shfl_xor(o1, 32);
    if (lane < 32) {
        float2* op = (float2*)(out + (size_t)w * 64 + 2 * lane);
        if (FIRST) {
            *op = make_float2(o0 * 0.125f, o1 * 0.125f);
        } else {
            float2 tv = *op;
            tv.x += o0 * 0.125f; tv.y += o1 * 0.125f;
            *op = tv;
        }
    }
}

// ---------------- gated residual + LN + relu (layer 0) ----------------
__global__ __launch_bounds__(256) void gres0_k(const float* __restrict__ x, const float* __restrict__ res,
                                               const float* __restrict__ gw,
                                               const float* __restrict__ lng, const float* __restrict__ lnb,
                                               float* __restrict__ h1, int n) {
    int w = (blockIdx.x * 256 + threadIdx.x) >> 6;
    int lane = threadIdx.x & 63;
    if (w >= n) return;
    size_t base = (size_t)w * 128;
    float x1 = x[base + lane], x2 = x[base + lane + 64];
    float r1 = res[base + lane], r2 = res[base + lane + 64];
    float ca1 = gw[lane] + gw[256 + lane];
    float ca2 = gw[lane + 64] + gw[256 + lane + 64];
    float cr1 = gw[128 + lane] - gw[256 + lane];
    float cr2 = gw[128 + lane + 64] - gw[256 + lane + 64];
    float dot = x1 * ca1 + x2 * ca2 + r1 * cr1 + r2 * cr2;
#pragma unroll
    for (int off = 1; off < 64; off <<= 1) dot += __shfl_xor(dot, off);
    float g = 1.f / (1.f + __expf(-dot));
    float o1 = x1 * g + r1 * (1.f - g);
    float o2 = x2 * g + r2 * (1.f - g);
    float s = o1 + o2;
#pragma unroll
    for (int off = 1; off < 64; off <<= 1) s += __shfl_xor(s, off);
    float mu = s * (1.f / 128.f);
    float d1 = o1 - mu, d2 = o2 - mu;
    float vs = d1 * d1 + d2 * d2;
#pragma unroll
    for (int off = 1; off < 64; off <<= 1) vs += __shfl_xor(vs, off);
    float rstd = rsqrtf(vs * (1.f / 128.f) + 1e-5f);
    float y1 = d1 * rstd * lng[lane] + lnb[lane];
    float y2 = d2 * rstd * lng[lane + 64] + lnb[lane + 64];
    h1[base + lane] = fmaxf(y1, 0.f);
    h1[base + lane + 64] = fmaxf(y2, 0.f);
}

// ---------------- gated residual only (layer 1, d=64) ----------------
__global__ __launch_bounds__(256) void gres1_k(const float* __restrict__ x, const float* __restrict__ res,
                                               const float* __restrict__ gw,
                                               float* __restrict__ out, int n) {
    int w = (blockIdx.x * 256 + threadIdx.x) >> 6;
    int lane = threadIdx.x & 63;
    if (w >= n) return;
    size_t base = (size_t)w * 64;
    float xv = x[base + lane];
    float rv = res[base + lane];
    float ca = gw[lane] + gw[128 + lane];
    float cr = gw[64 + lane] - gw[128 + lane];
    float dot = xv * ca + rv * cr;
#pragma unroll
    for (int off = 1; off < 64; off <<= 1) dot += __shfl_xor(dot, off);
    float g = 1.f / (1.f + __expf(-dot));
    out[base + lane] = xv * g + rv * (1.f - g);
}

extern "C" void kernel_launch(void* const* d_in, const int* in_sizes, int n_in,
                              void* d_out, int out_size, void* d_ws, size_t ws_size,
                              hipStream_t stream) {
    const float* x    = (const float*)d_in[0];
    const int*   src  = (const int*)d_in[1];
    const int*   dst  = (const int*)d_in[2];
    const float* in_W = (const float*)d_in[3];
    const float* in_b = (const float*)d_in[4];
    const float* q0W = (const float*)d_in[5];  const float* q0b = (const float*)d_in[6];
    const float* k0W = (const float*)d_in[7];  const float* k0b = (const float*)d_in[8];
    const float* v0W = (const float*)d_in[9];  const float* v0b = (const float*)d_in[10];
    const float* r0W = (const float*)d_in[11]; const float* r0b = (const float*)d_in[12];
    const float* g0W = (const float*)d_in[13];
    const float* ln0g = (const float*)d_in[14]; const float* ln0b = (const float*)d_in[15];
    const float* q1W = (const float*)d_in[16]; const float* q1b = (const float*)d_in[17];
    const float* k1W = (const float*)d_in[18]; const float* k1b = (const float*)d_in[19];
    const float* v1W = (const float*)d_in[20]; const float* v1b = (const float*)d_in[21];
    const float* r1W = (const float*)d_in[22]; const float* r1b = (const float*)d_in[23];
    const float* g1W = (const float*)d_in[24];

    const int N = in_sizes[0] / 256;   // 100000
    const int E = in_sizes[1];         // 1600000
    (void)ws_size; (void)n_in; (void)out_size;

    // ---- workspace layout with reuse: peak ~186 MB ----
    auto rnd = [](size_t b) { return (b + 255) & ~(size_t)255; };
    char* base = (char*)d_ws;
    const size_t S_bf = rnd((size_t)N * 128 * 2);   // 25.6 MB (N x 128 bf16)
    const size_t S_f  = rnd((size_t)N * 128 * 4);   // 51.2 MB (N x 128 f32)
    size_t o = 0;
    int* row_off = (int*)(base + o); o += rnd(((size_t)N + 1) * 4);
    int* csr     = (int*)(base + o); o += rnd((size_t)E * 4);
    const size_t R0 = o;                      // 51.2 MB: h -> a0 -> {res1o, a1}
    const size_t R1 = R0 + S_f;               // 76.8 MB: q0,k0,v0 -> h1 (2 slots) + q_h (3rd)
    const size_t R2 = R1 + 3 * S_bf;          // 51.2 MB: res0o -> {k_h, v_h}
    float* h     = (float*)(base + R0);
    float* a0    = (float*)(base + R0);
    float* res1o = (float*)(base + R0);
    float* a1    = (float*)(base + R0 + rnd((size_t)N * 64 * 4));
    int* cnt     = (int*)(base + R0);                       // CSR transients (die before h)
    int* cur     = (int*)(base + R0 + rnd((size_t)N * 4));
    int* bsum    = (int*)(base + R0 + 2 * rnd((size_t)N * 4));
    u16* q0  = (u16*)(base + R1);
    u16* k0  = (u16*)(base + R1 + S_bf);
    u16* v0  = (u16*)(base + R1 + 2 * S_bf);
    float* h1 = (float*)(base + R1);          // overlays q0+k0 (dead after attn0)
    u16* q_h  = (u16*)(base + R1 + 2 * S_bf); // overlays v0
    float* res0o = (float*)(base + R2);
    u16* k_h  = (u16*)(base + R2);            // overlays res0o (dead after gres0)
    u16* v_h  = (u16*)(base + R2 + S_bf);

    dim3 blk(256);
    int nwb = (N * 64 + 255) / 256;   // one wave per node
    int nb  = (N + 255) / 256;        // 391 (<= 512)

    // ---- CSR build ----
    zero2_k<<<nb, blk, 0, stream>>>(cnt, cur, N);
    hist_k<<<(E + 255) / 256, blk, 0, stream>>>(dst, cnt, E);
    blocksum_k<<<nb, blk, 0, stream>>>(cnt, bsum, N);
    scanb_k<<<1, 512, 0, stream>>>(bsum, nb);
    scanc_k<<<nb, blk, 0, stream>>>(cnt, bsum, row_off, N, E);
    scatter_k<<<(E + 255) / 256, blk, 0, stream>>>(src, dst, row_off, cur, csr, E);

    // ---- layer 0 ----
    dim3 g128(2, (N + 63) / 64);
    gemm_k<false><<<g128, blk, 0, stream>>>(x, in_W, in_b, h, N, 128, 256, 128, 128);
    gemm_k<true><<<g128, blk, 0, stream>>>(h, q0W, q0b, q0, N, 128, 128, 128, 128);
    gemm_k<true><<<g128, blk, 0, stream>>>(h, k0W, k0b, k0, N, 128, 128, 128, 128);
    gemm_k<true><<<g128, blk, 0, stream>>>(h, v0W, v0b, v0, N, 128, 128, 128, 128);
    gemm_k<false><<<g128, blk, 0, stream>>>(h, r0W, r0b, res0o, N, 128, 128, 128, 128);

    attn0_k<<<nwb, blk, 0, stream>>>(q0, k0, v0, row_off, csr, a0, N);
    gres0_k<<<nwb, blk, 0, stream>>>(a0, res0o, g0W, ln0g, ln0b, h1, N);

    // ---- layer 1: res path, then 4 passes of 2 heads each ----
    dim3 g64(1, (N + 63) / 64);
    gemm_k<false><<<g64, blk, 0, stream>>>(h1, r1W, r1b, res1o, N, 64, 128, 64, 64);

    for (int p = 0; p < 4; ++p) {
        int co = p * 128;   // column offset into the (128 x 512) qkv weights
        gemm_k<true><<<g128, blk, 0, stream>>>(h1, q1W + co, q1b + co, q_h, N, 128, 128, 512, 128);
        gemm_k<true><<<g128, blk, 0, stream>>>(h1, k1W + co, k1b + co, k_h, N, 128, 128, 512, 128);
        gemm_k<true><<<g128, blk, 0, stream>>>(h1, v1W + co, v1b + co, v_h, N, 128, 128, 512, 128);
        if (p == 0) attn1_k<true><<<nwb, blk, 0, stream>>>(q_h, k_h, v_h, row_off, csr, a1, N);
        else        attn1_k<false><<<nwb, blk, 0, stream>>>(q_h, k_h, v_h, row_off, csr, a1, N);
    }

    gres1_k<<<nwb, blk, 0, stream>>>(a1, res1o, g1W, (float*)d_out, N);
}

// Round 3
// 1462.706 us; speedup vs baseline: 1.5316x; 1.5316x over previous
//
#include <hip/hip_runtime.h>

// GraphTransformerModel: 2-layer graph attention network.
// CSR build -> [bf16 MFMA GEMMs] -> attn0 (per-dst wave, unroll-4) -> gres0+LN
// -> per-2-head passes {qkv slice MFMA GEMMs -> attn1 accumulate} -> gres1.
// Weights pre-transposed to [N][K] bf16; activations h/h1/x_bf in bf16;
// all accumulation f32. Peak workspace ~188 MB.

typedef unsigned short u16;
typedef __attribute__((ext_vector_type(8))) unsigned short ushort8;
typedef __attribute__((ext_vector_type(8))) short short8v;   // 8 bf16 (4 VGPRs)
typedef __attribute__((ext_vector_type(4))) float f32x4;

__device__ __forceinline__ float bf2f(unsigned short u) {
    return __uint_as_float(((unsigned)u) << 16);
}
__device__ __forceinline__ unsigned short f2bf(float f) {
    unsigned u = __float_as_uint(f);
    unsigned r = 0x7fffu + ((u >> 16) & 1u);   // round-to-nearest-even
    return (unsigned short)((u + r) >> 16);
}

// ---------------- weight prep: W[K][N] f32 -> Wt[N][K] bf16 ----------------
__global__ void wtr_k(const float* __restrict__ W, u16* __restrict__ Wt, int K, int N) {
    int i = blockIdx.x * 256 + threadIdx.x;
    if (i >= K * N) return;
    int k = i / N, n = i - k * N;
    Wt[(size_t)n * K + k] = f2bf(W[i]);
}

// ---------------- f32 -> bf16 convert (8 elems/thread) ----------------
__global__ void cvt_k(const float* __restrict__ in, u16* __restrict__ out, int n8) {
    int i = blockIdx.x * 256 + threadIdx.x;
    if (i >= n8) return;
    float4 a = *(const float4*)(in + (size_t)i * 8);
    float4 b = *(const float4*)(in + (size_t)i * 8 + 4);
    ushort8 o = {f2bf(a.x), f2bf(a.y), f2bf(a.z), f2bf(a.w),
                 f2bf(b.x), f2bf(b.y), f2bf(b.z), f2bf(b.w)};
    *(ushort8*)(out + (size_t)i * 8) = o;
}

// ---------------- MFMA GEMM: C[M,N] = A[M,K](bf16) @ Bt[N,K](bf16)^T + bias ----------------
// BM=128 (grid.x blocks), N<=128 single tile. BK=64, 256 thr = 4 waves (2x2 of 64x64).
template <bool OUTBF16>
__global__ __launch_bounds__(256) void mgemm_k(const u16* __restrict__ A,
                                               const u16* __restrict__ Bt,
                                               const float* __restrict__ bias,
                                               void* __restrict__ C,
                                               int M, int N, int K, int ldc) {
    __shared__ __align__(16) u16 As[128][72];   // pad 64->72: rows 2-way bank alias only
    __shared__ __align__(16) u16 Bs[128][72];
    const int bm = blockIdx.x * 128;
    const int t = threadIdx.x;
    const int lane = t & 63;
    const int wid = t >> 6;
    const int wm = (wid >> 1) * 64, wn = (wid & 1) * 64;
    f32x4 acc[4][4] = {};
    for (int k0 = 0; k0 < K; k0 += 64) {
#pragma unroll
        for (int c = 0; c < 4; ++c) {          // stage 128x64 A and Bt tiles
            int ch = c * 256 + t;              // wave reads 64 consecutive 16B chunks
            int r = ch >> 3, off = (ch & 7) * 8;
            short8v av = {};
            if (bm + r < M) av = *(const short8v*)(A + (size_t)(bm + r) * K + k0 + off);
            *(short8v*)(&As[r][off]) = av;
            short8v bv = {};
            if (r < N) bv = *(const short8v*)(Bt + (size_t)r * K + k0 + off);
            *(short8v*)(&Bs[r][off]) = bv;
        }
        __syncthreads();
#pragma unroll
        for (int ks = 0; ks < 2; ++ks) {
            int kr = ks * 32 + (lane >> 4) * 8;
            short8v af[4], bfr[4];
#pragma unroll
            for (int i = 0; i < 4; ++i) {
                af[i]  = *(const short8v*)(&As[wm + i * 16 + (lane & 15)][kr]);
                bfr[i] = *(const short8v*)(&Bs[wn + i * 16 + (lane & 15)][kr]);
            }
#pragma unroll
            for (int mi = 0; mi < 4; ++mi)
#pragma unroll
                for (int ni = 0; ni < 4; ++ni)
                    acc[mi][ni] = __builtin_amdgcn_mfma_f32_16x16x32_bf16(
                        af[mi], bfr[ni], acc[mi][ni], 0, 0, 0);
        }
        __syncthreads();
    }
    // epilogue: C/D frag layout col=lane&15, row=(lane>>4)*4+j
#pragma unroll
    for (int ni = 0; ni < 4; ++ni) {
        int ccol = wn + ni * 16 + (lane & 15);
        if (ccol >= N) continue;
        float bs = bias[ccol];
#pragma unroll
        for (int mi = 0; mi < 4; ++mi) {
#pragma unroll
            for (int j = 0; j < 4; ++j) {
                int crow = bm + wm + mi * 16 + (lane >> 4) * 4 + j;
                if (crow >= M) continue;
                float val = acc[mi][ni][j] + bs;
                if (OUTBF16) ((u16*)C)[(size_t)crow * ldc + ccol] = f2bf(val);
                else         ((float*)C)[(size_t)crow * ldc + ccol] = val;
            }
        }
    }
}

// ---------------- CSR build ----------------
__global__ void zero2_k(int* __restrict__ a, int* __restrict__ b, int n) {
    int i = blockIdx.x * 256 + threadIdx.x;
    if (i < n) { a[i] = 0; b[i] = 0; }
}

__global__ void hist_k(const int* __restrict__ dst, int* __restrict__ cnt, int E) {
    int i = blockIdx.x * 256 + threadIdx.x;
    if (i < E) atomicAdd(&cnt[dst[i]], 1);
}

__global__ void blocksum_k(const int* __restrict__ cnt, int* __restrict__ bsum, int n) {
    __shared__ int sd[256];
    int i = blockIdx.x * 256 + threadIdx.x;
    sd[threadIdx.x] = (i < n) ? cnt[i] : 0;
    __syncthreads();
    for (int off = 128; off > 0; off >>= 1) {
        if (threadIdx.x < off) sd[threadIdx.x] += sd[threadIdx.x + off];
        __syncthreads();
    }
    if (threadIdx.x == 0) bsum[blockIdx.x] = sd[0];
}

__global__ void scanb_k(int* bsum, int nb) {
    __shared__ int tmp[512];
    int t = threadIdx.x;
    tmp[t] = (t < nb) ? bsum[t] : 0;
    __syncthreads();
    for (int off = 1; off < 512; off <<= 1) {
        int v = (t >= off) ? tmp[t - off] : 0;
        __syncthreads();
        tmp[t] += v;
        __syncthreads();
    }
    if (t < nb) bsum[t] = (t ? tmp[t - 1] : 0);
}

__global__ void scanc_k(const int* __restrict__ cnt, const int* __restrict__ bsum,
                        int* __restrict__ row_off, int n, int E) {
    __shared__ int tmp[256];
    int b = blockIdx.x, t = threadIdx.x;
    int i = b * 256 + t;
    int own = (i < n) ? cnt[i] : 0;
    tmp[t] = own;
    __syncthreads();
    for (int off = 1; off < 256; off <<= 1) {
        int v = (t >= off) ? tmp[t - off] : 0;
        __syncthreads();
        tmp[t] += v;
        __syncthreads();
    }
    if (i < n) row_off[i] = bsum[b] + tmp[t] - own;
    if (b == 0 && t == 0) row_off[n] = E;
}

__global__ void scatter_k(const int* __restrict__ src, const int* __restrict__ dst,
                          const int* __restrict__ row_off, int* __restrict__ cur,
                          int* __restrict__ csr_src, int E) {
    int i = blockIdx.x * 256 + threadIdx.x;
    if (i < E) {
        int d = dst[i];
        int pos = row_off[d] + atomicAdd(&cur[d], 1);
        csr_src[pos] = src[i];
    }
}

// ---------------- attention layer 0: 8 heads x d=16, F=128, concat ----------------
// one wave/node; lane l holds feats 2l,2l+1 (head l>>3); 8-lane-group reduce. Unroll 4.
__global__ __launch_bounds__(256) void attn0_k(const u16* __restrict__ q, const u16* __restrict__ k,
                                               const u16* __restrict__ v,
                                               const int* __restrict__ row_off,
                                               const int* __restrict__ csr,
                                               float* __restrict__ out, int n) {
    int w = (blockIdx.x * 256 + threadIdx.x) >> 6;
    int lane = threadIdx.x & 63;
    if (w >= n) return;
    int beg = row_off[w], end = row_off[w + 1];
    unsigned kv = *(const unsigned*)(k + ((size_t)w << 7) + 2 * lane);
    float k0f = bf2f((u16)kv), k1f = bf2f((u16)(kv >> 16));
    float den = 0.f, num0 = 0.f, num1 = 0.f;
    int e = beg;
    for (; e + 4 <= end; e += 4) {
        int s0 = csr[e], s1 = csr[e + 1], s2 = csr[e + 2], s3 = csr[e + 3];
        unsigned qa = *(const unsigned*)(q + ((size_t)s0 << 7) + 2 * lane);
        unsigned qb = *(const unsigned*)(q + ((size_t)s1 << 7) + 2 * lane);
        unsigned qc = *(const unsigned*)(q + ((size_t)s2 << 7) + 2 * lane);
        unsigned qd = *(const unsigned*)(q + ((size_t)s3 << 7) + 2 * lane);
        unsigned va = *(const unsigned*)(v + ((size_t)s0 << 7) + 2 * lane);
        unsigned vb = *(const unsigned*)(v + ((size_t)s1 << 7) + 2 * lane);
        unsigned vc = *(const unsigned*)(v + ((size_t)s2 << 7) + 2 * lane);
        unsigned vd = *(const unsigned*)(v + ((size_t)s3 << 7) + 2 * lane);
        float pa = bf2f((u16)qa) * k0f + bf2f((u16)(qa >> 16)) * k1f;
        float pb = bf2f((u16)qb) * k0f + bf2f((u16)(qb >> 16)) * k1f;
        float pc = bf2f((u16)qc) * k0f + bf2f((u16)(qc >> 16)) * k1f;
        float pd = bf2f((u16)qd) * k0f + bf2f((u16)(qd >> 16)) * k1f;
#pragma unroll
        for (int off = 1; off < 8; off <<= 1) {
            pa += __shfl_xor(pa, off); pb += __shfl_xor(pb, off);
            pc += __shfl_xor(pc, off); pd += __shfl_xor(pd, off);
        }
        float wa = __expf(pa * 0.25f), wb = __expf(pb * 0.25f);
        float wc = __expf(pc * 0.25f), wd = __expf(pd * 0.25f);
        den += (wa + wb) + (wc + wd);
        num0 = fmaf(wa, bf2f((u16)va), num0);
        num1 = fmaf(wa, bf2f((u16)(va >> 16)), num1);
        num0 = fmaf(wb, bf2f((u16)vb), num0);
        num1 = fmaf(wb, bf2f((u16)(vb >> 16)), num1);
        num0 = fmaf(wc, bf2f((u16)vc), num0);
        num1 = fmaf(wc, bf2f((u16)(vc >> 16)), num1);
        num0 = fmaf(wd, bf2f((u16)vd), num0);
        num1 = fmaf(wd, bf2f((u16)(vd >> 16)), num1);
    }
    for (; e < end; ++e) {
        int s = csr[e];
        unsigned qv = *(const unsigned*)(q + ((size_t)s << 7) + 2 * lane);
        float p = bf2f((u16)qv) * k0f + bf2f((u16)(qv >> 16)) * k1f;
        p += __shfl_xor(p, 1);
        p += __shfl_xor(p, 2);
        p += __shfl_xor(p, 4);
        float wt = __expf(p * 0.25f);
        den += wt;
        unsigned vv = *(const unsigned*)(v + ((size_t)s << 7) + 2 * lane);
        num0 = fmaf(wt, bf2f((u16)vv), num0);
        num1 = fmaf(wt, bf2f((u16)(vv >> 16)), num1);
    }
    float inv = (end > beg) ? 1.f / den : 0.f;
    *(float2*)(out + ((size_t)w << 7) + 2 * lane) = make_float2(num0 * inv, num1 * inv);
}

// ---------------- attention layer 1 (one 2-head pass): d=64, accumulate mean ----------------
template <bool FIRST>
__global__ __launch_bounds__(256) void attn1_k(const u16* __restrict__ q, const u16* __restrict__ k,
                                               const u16* __restrict__ v,
                                               const int* __restrict__ row_off,
                                               const int* __restrict__ csr,
                                               float* __restrict__ out, int n) {
    int w = (blockIdx.x * 256 + threadIdx.x) >> 6;
    int lane = threadIdx.x & 63;
    if (w >= n) return;
    int beg = row_off[w], end = row_off[w + 1];
    unsigned kv = *(const unsigned*)(k + ((size_t)w << 7) + 2 * lane);
    float k0f = bf2f((u16)kv), k1f = bf2f((u16)(kv >> 16));
    float den = 0.f, num0 = 0.f, num1 = 0.f;
    int e = beg;
    for (; e + 4 <= end; e += 4) {
        int s0 = csr[e], s1 = csr[e + 1], s2 = csr[e + 2], s3 = csr[e + 3];
        unsigned qa = *(const unsigned*)(q + ((size_t)s0 << 7) + 2 * lane);
        unsigned qb = *(const unsigned*)(q + ((size_t)s1 << 7) + 2 * lane);
        unsigned qc = *(const unsigned*)(q + ((size_t)s2 << 7) + 2 * lane);
        unsigned qd = *(const unsigned*)(q + ((size_t)s3 << 7) + 2 * lane);
        unsigned va = *(const unsigned*)(v + ((size_t)s0 << 7) + 2 * lane);
        unsigned vb = *(const unsigned*)(v + ((size_t)s1 << 7) + 2 * lane);
        unsigned vc = *(const unsigned*)(v + ((size_t)s2 << 7) + 2 * lane);
        unsigned vd = *(const unsigned*)(v + ((size_t)s3 << 7) + 2 * lane);
        float pa = bf2f((u16)qa) * k0f + bf2f((u16)(qa >> 16)) * k1f;
        float pb = bf2f((u16)qb) * k0f + bf2f((u16)(qb >> 16)) * k1f;
        float pc = bf2f((u16)qc) * k0f + bf2f((u16)(qc >> 16)) * k1f;
        float pd = bf2f((u16)qd) * k0f + bf2f((u16)(qd >> 16)) * k1f;
#pragma unroll
        for (int off = 1; off < 32; off <<= 1) {
            pa += __shfl_xor(pa, off); pb += __shfl_xor(pb, off);
            pc += __shfl_xor(pc, off); pd += __shfl_xor(pd, off);
        }
        float wa = __expf(pa * 0.125f), wb = __expf(pb * 0.125f);
        float wc = __expf(pc * 0.125f), wd = __expf(pd * 0.125f);
        den += (wa + wb) + (wc + wd);
        num0 = fmaf(wa, bf2f((u16)va), num0);
        num1 = fmaf(wa, bf2f((u16)(va >> 16)), num1);
        num0 = fmaf(wb, bf2f((u16)vb), num0);
        num1 = fmaf(wb, bf2f((u16)(vb >> 16)), num1);
        num0 = fmaf(wc, bf2f((u16)vc), num0);
        num1 = fmaf(wc, bf2f((u16)(vc >> 16)), num1);
        num0 = fmaf(wd, bf2f((u16)vd), num0);
        num1 = fmaf(wd, bf2f((u16)(vd >> 16)), num1);
    }
    for (; e < end; ++e) {
        int s = csr[e];
        unsigned qv = *(const unsigned*)(q + ((size_t)s << 7) + 2 * lane);
        float p = bf2f((u16)qv) * k0f + bf2f((u16)(qv >> 16)) * k1f;
#pragma unroll
        for (int off = 1; off < 32; off <<= 1) p += __shfl_xor(p, off);
        float wt = __expf(p * 0.125f);
        den += wt;
        unsigned vv = *(const unsigned*)(v + ((size_t)s << 7) + 2 * lane);
        num0 = fmaf(wt, bf2f((u16)vv), num0);
        num1 = fmaf(wt, bf2f((u16)(vv >> 16)), num1);
    }
    float inv = (end > beg) ? 1.f / den : 0.f;
    float o0 = num0 * inv, o1 = num1 * inv;
    o0 += __shfl_xor(o0, 32);   // combine the two heads (same output dim)
    o1 += __shfl_xor(o1, 32);
    if (lane < 32) {
        float2* op = (float2*)(out + ((size_t)w << 6) + 2 * lane);
        if (FIRST) {
            *op = make_float2(o0 * 0.125f, o1 * 0.125f);
        } else {
            float2 tv = *op;
            tv.x += o0 * 0.125f; tv.y += o1 * 0.125f;
            *op = tv;
        }
    }
}

// ---------------- gated residual + LN + relu (layer 0), bf16 h1 out ----------------
__global__ __launch_bounds__(256) void gres0_k(const float* __restrict__ x, const float* __restrict__ res,
                                               const float* __restrict__ gw,
                                               const float* __restrict__ lng, const float* __restrict__ lnb,
                                               u16* __restrict__ h1, int n) {
    int w = (blockIdx.x * 256 + threadIdx.x) >> 6;
    int lane = threadIdx.x & 63;
    if (w >= n) return;
    size_t base = (size_t)w * 128;
    float x1 = x[base + lane], x2 = x[base + lane + 64];
    float r1 = res[base + lane], r2 = res[base + lane + 64];
    float ca1 = gw[lane] + gw[256 + lane];
    float ca2 = gw[lane + 64] + gw[256 + lane + 64];
    float cr1 = gw[128 + lane] - gw[256 + lane];
    float cr2 = gw[128 + lane + 64] - gw[256 + lane + 64];
    float dot = x1 * ca1 + x2 * ca2 + r1 * cr1 + r2 * cr2;
#pragma unroll
    for (int off = 1; off < 64; off <<= 1) dot += __shfl_xor(dot, off);
    float g = 1.f / (1.f + __expf(-dot));
    float o1 = x1 * g + r1 * (1.f - g);
    float o2 = x2 * g + r2 * (1.f - g);
    float s = o1 + o2;
#pragma unroll
    for (int off = 1; off < 64; off <<= 1) s += __shfl_xor(s, off);
    float mu = s * (1.f / 128.f);
    float d1 = o1 - mu, d2 = o2 - mu;
    float vs = d1 * d1 + d2 * d2;
#pragma unroll
    for (int off = 1; off < 64; off <<= 1) vs += __shfl_xor(vs, off);
    float rstd = rsqrtf(vs * (1.f / 128.f) + 1e-5f);
    float y1 = d1 * rstd * lng[lane] + lnb[lane];
    float y2 = d2 * rstd * lng[lane + 64] + lnb[lane + 64];
    h1[base + lane] = f2bf(fmaxf(y1, 0.f));
    h1[base + lane + 64] = f2bf(fmaxf(y2, 0.f));
}

// ---------------- gated residual only (layer 1, d=64) ----------------
__global__ __launch_bounds__(256) void gres1_k(const float* __restrict__ x, const float* __restrict__ res,
                                               const float* __restrict__ gw,
                                               float* __restrict__ out, int n) {
    int w = (blockIdx.x * 256 + threadIdx.x) >> 6;
    int lane = threadIdx.x & 63;
    if (w >= n) return;
    size_t base = (size_t)w * 64;
    float xv = x[base + lane];
    float rv = res[base + lane];
    float ca = gw[lane] + gw[128 + lane];
    float cr = gw[64 + lane] - gw[128 + lane];
    float dot = xv * ca + rv * cr;
#pragma unroll
    for (int off = 1; off < 64; off <<= 1) dot += __shfl_xor(dot, off);
    float g = 1.f / (1.f + __expf(-dot));
    out[base + lane] = xv * g + rv * (1.f - g);
}

extern "C" void kernel_launch(void* const* d_in, const int* in_sizes, int n_in,
                              void* d_out, int out_size, void* d_ws, size_t ws_size,
                              hipStream_t stream) {
    const float* x    = (const float*)d_in[0];
    const int*   src  = (const int*)d_in[1];
    const int*   dst  = (const int*)d_in[2];
    const float* in_W = (const float*)d_in[3];
    const float* in_b = (const float*)d_in[4];
    const float* q0W = (const float*)d_in[5];  const float* q0b = (const float*)d_in[6];
    const float* k0W = (const float*)d_in[7];  const float* k0b = (const float*)d_in[8];
    const float* v0W = (const float*)d_in[9];  const float* v0b = (const float*)d_in[10];
    const float* r0W = (const float*)d_in[11]; const float* r0b = (const float*)d_in[12];
    const float* g0W = (const float*)d_in[13];
    const float* ln0g = (const float*)d_in[14]; const float* ln0b = (const float*)d_in[15];
    const float* q1W = (const float*)d_in[16]; const float* q1b = (const float*)d_in[17];
    const float* k1W = (const float*)d_in[18]; const float* k1b = (const float*)d_in[19];
    const float* v1W = (const float*)d_in[20]; const float* v1b = (const float*)d_in[21];
    const float* r1W = (const float*)d_in[22]; const float* r1b = (const float*)d_in[23];
    const float* g1W = (const float*)d_in[24];

    const int N = in_sizes[0] / 256;   // 100000
    const int E = in_sizes[1];         // 1600000
    (void)ws_size; (void)n_in; (void)out_size;

    // ---- workspace layout with reuse: peak ~188 MB ----
    auto rnd = [](size_t b) { return (b + 255) & ~(size_t)255; };
    char* base = (char*)d_ws;
    const size_t S_bf = rnd((size_t)N * 128 * 2);   // 25.6 MB (N x 128 bf16)
    const size_t S_f  = rnd((size_t)N * 128 * 4);   // 51.2 MB (N x 128 f32)
    size_t o = 0;
    int* row_off = (int*)(base + o); o += rnd(((size_t)N + 1) * 4);
    int* csr     = (int*)(base + o); o += rnd((size_t)E * 4);
    // transposed bf16 weights (persistent, ~0.6 MB)
    u16* inWt  = (u16*)(base + o); o += rnd((size_t)128 * 256 * 2);
    u16* q0t   = (u16*)(base + o); o += rnd((size_t)128 * 128 * 2);
    u16* k0t   = (u16*)(base + o); o += rnd((size_t)128 * 128 * 2);
    u16* v0t   = (u16*)(base + o); o += rnd((size_t)128 * 128 * 2);
    u16* r0t   = (u16*)(base + o); o += rnd((size_t)128 * 128 * 2);
    u16* q1t   = (u16*)(base + o); o += rnd((size_t)512 * 128 * 2);
    u16* k1t   = (u16*)(base + o); o += rnd((size_t)512 * 128 * 2);
    u16* v1t   = (u16*)(base + o); o += rnd((size_t)512 * 128 * 2);
    u16* r1t   = (u16*)(base + o); o += rnd((size_t)64 * 128 * 2);
    const size_t R0 = o;                 // 51.2 MB: cnt/cur/bsum -> h(bf16) -> a0 -> {res1o, a1}
    const size_t R1 = R0 + S_f;          // 76.8 MB: x_bf -> q0,k0,v0 -> h1 + q_h
    const size_t R2 = R1 + 3 * S_bf;     // 51.2 MB: res0o -> {k_h, v_h}
    int* cnt  = (int*)(base + R0);
    int* cur  = (int*)(base + R0 + rnd((size_t)N * 4));
    int* bsum = (int*)(base + R0 + 2 * rnd((size_t)N * 4));
    u16*   h     = (u16*)(base + R0);
    float* a0    = (float*)(base + R0);
    float* res1o = (float*)(base + R0);
    float* a1    = (float*)(base + R0 + rnd((size_t)N * 64 * 4));
    u16* x_bf = (u16*)(base + R1);                 // N x 256 bf16 (51.2 MB), dies after in-GEMM
    u16* q0   = (u16*)(base + R1);
    u16* k0   = (u16*)(base + R1 + S_bf);
    u16* v0   = (u16*)(base + R1 + 2 * S_bf);
    u16* h1   = (u16*)(base + R1);                 // overlays q0 slot (dead after attn0)
    u16* q_h  = (u16*)(base + R1 + 2 * S_bf);      // overlays v0
    float* res0o = (float*)(base + R2);
    u16* k_h  = (u16*)(base + R2);                 // overlays res0o (dead after gres0)
    u16* v_h  = (u16*)(base + R2 + S_bf);

    dim3 blk(256);
    int nwb = (N * 64 + 255) / 256;   // one wave per node
    int nb  = (N + 255) / 256;        // 391 (<= 512)
    int mblocks = (N + 127) / 128;    // 782

    // ---- weight prep + input convert (overlap with CSR build) ----
    wtr_k<<<(256 * 128 + 255) / 256, blk, 0, stream>>>(in_W, inWt, 256, 128);
    wtr_k<<<(128 * 128 + 255) / 256, blk, 0, stream>>>(q0W, q0t, 128, 128);
    wtr_k<<<(128 * 128 + 255) / 256, blk, 0, stream>>>(k0W, k0t, 128, 128);
    wtr_k<<<(128 * 128 + 255) / 256, blk, 0, stream>>>(v0W, v0t, 128, 128);
    wtr_k<<<(128 * 128 + 255) / 256, blk, 0, stream>>>(r0W, r0t, 128, 128);
    wtr_k<<<(128 * 512 + 255) / 256, blk, 0, stream>>>(q1W, q1t, 128, 512);
    wtr_k<<<(128 * 512 + 255) / 256, blk, 0, stream>>>(k1W, k1t, 128, 512);
    wtr_k<<<(128 * 512 + 255) / 256, blk, 0, stream>>>(v1W, v1t, 128, 512);
    wtr_k<<<(128 * 64 + 255) / 256, blk, 0, stream>>>(r1W, r1t, 128, 64);
    cvt_k<<<(N * 32 + 255) / 256, blk, 0, stream>>>(x, x_bf, N * 32);   // N*256/8

    // ---- CSR build ----
    zero2_k<<<nb, blk, 0, stream>>>(cnt, cur, N);
    hist_k<<<(E + 255) / 256, blk, 0, stream>>>(dst, cnt, E);
    blocksum_k<<<nb, blk, 0, stream>>>(cnt, bsum, N);
    scanb_k<<<1, 512, 0, stream>>>(bsum, nb);
    scanc_k<<<nb, blk, 0, stream>>>(cnt, bsum, row_off, N, E);
    scatter_k<<<(E + 255) / 256, blk, 0, stream>>>(src, dst, row_off, cur, csr, E);

    // ---- layer 0 (bf16 MFMA GEMMs) ----
    mgemm_k<true><<<mblocks, blk, 0, stream>>>(x_bf, inWt, in_b, h, N, 128, 256, 128);
    mgemm_k<true><<<mblocks, blk, 0, stream>>>(h, q0t, q0b, q0, N, 128, 128, 128);
    mgemm_k<true><<<mblocks, blk, 0, stream>>>(h, k0t, k0b, k0, N, 128, 128, 128);
    mgemm_k<true><<<mblocks, blk, 0, stream>>>(h, v0t, v0b, v0, N, 128, 128, 128);
    mgemm_k<false><<<mblocks, blk, 0, stream>>>(h, r0t, r0b, res0o, N, 128, 128, 128);

    attn0_k<<<nwb, blk, 0, stream>>>(q0, k0, v0, row_off, csr, a0, N);
    gres0_k<<<nwb, blk, 0, stream>>>(a0, res0o, g0W, ln0g, ln0b, h1, N);

    // ---- layer 1: res path, then 4 passes of 2 heads each ----
    mgemm_k<false><<<mblocks, blk, 0, stream>>>(h1, r1t, r1b, res1o, N, 64, 128, 64);

    for (int p = 0; p < 4; ++p) {
        size_t co = (size_t)p * 128 * 128;   // Bt row offset (output cols p*128..)
        mgemm_k<true><<<mblocks, blk, 0, stream>>>(h1, q1t + co, q1b + p * 128, q_h, N, 128, 128, 128);
        mgemm_k<true><<<mblocks, blk, 0, stream>>>(h1, k1t + co, k1b + p * 128, k_h, N, 128, 128, 128);
        mgemm_k<true><<<mblocks, blk, 0, stream>>>(h1, v1t + co, v1b + p * 128, v_h, N, 128, 128, 128);
        if (p == 0) attn1_k<true><<<nwb, blk, 0, stream>>>(q_h, k_h, v_h, row_off, csr, a1, N);
        else        attn1_k<false><<<nwb, blk, 0, stream>>>(q_h, k_h, v_h, row_off, csr, a1, N);
    }

    gres1_k<<<nwb, blk, 0, stream>>>(a1, res1o, g1W, (float*)d_out, N);
}

// Round 5
// 1298.065 us; speedup vs baseline: 1.7259x; 1.1268x over previous
//
#include <hip/hip_runtime.h>

// GraphTransformerModel: 2-layer graph attention network.
// CSR build -> fused bf16 MFMA GEMMs (full-K LDS staging, STATIC 69.6KB LDS)
// -> attn0 -> gres0+LN -> per-2-head passes {fused qkv1 GEMM -> attn1} -> gres1.
// q/k/v live in fused [N][384] bf16 buffers; all accumulation f32.
// Peak workspace ~186 MB.

typedef unsigned short u16;
typedef __attribute__((ext_vector_type(8))) unsigned short ushort8;
typedef __attribute__((ext_vector_type(8))) short short8v;   // 8 bf16 (4 VGPRs)
typedef __attribute__((ext_vector_type(4))) float f32x4;

__device__ __forceinline__ float bf2f(unsigned short u) {
    return __uint_as_float(((unsigned)u) << 16);
}
__device__ __forceinline__ unsigned short f2bf(float f) {
    unsigned u = __float_as_uint(f);
    unsigned r = 0x7fffu + ((u >> 16) & 1u);   // round-to-nearest-even
    return (unsigned short)((u + r) >> 16);
}

// ---------------- fused weight prep: all transposed bf16 weights in one kernel ----------------
// arena (u16): [0)=inWt[128][256]  [32768)=qkv0t[384][128]  [81920)=r0t[128][128]
//              [98304)=qkv1t[4][384][128]  [294912)=r1t[64][128]  total 303104
__global__ void prep_k(const float* __restrict__ inW,
                       const float* __restrict__ q0W, const float* __restrict__ k0W,
                       const float* __restrict__ v0W, const float* __restrict__ r0W,
                       const float* __restrict__ q1W, const float* __restrict__ k1W,
                       const float* __restrict__ v1W, const float* __restrict__ r1W,
                       u16* __restrict__ arena) {
    int i = blockIdx.x * 256 + threadIdx.x;
    if (i >= 303104) return;
    float val;
    if (i < 32768) {                       // inWt[n][k] = inW[k][n], K=256, N=128
        int n = i >> 8, k = i & 255;
        val = inW[k * 128 + n];
    } else if (i < 81920) {                // qkv0t
        int j = i - 32768;
        int r = j >> 7, kk = j & 127;
        int sec = r >> 7, c = r & 127;
        const float* s = (sec == 0) ? q0W : (sec == 1) ? k0W : v0W;
        val = s[kk * 128 + c];
    } else if (i < 98304) {                // r0t
        int j = i - 81920;
        int r = j >> 7, kk = j & 127;
        val = r0W[kk * 128 + r];
    } else if (i < 294912) {               // qkv1t[p][384][128]
        int j = i - 98304;
        int row = j >> 7, kk = j & 127;
        int p = row / 384, rr = row - p * 384;
        int sec = rr >> 7, c = p * 128 + (rr & 127);
        const float* s = (sec == 0) ? q1W : (sec == 1) ? k1W : v1W;
        val = s[kk * 512 + c];
    } else {                               // r1t[64][128]
        int j = i - 294912;
        int n = j >> 7, kk = j & 127;
        val = r1W[kk * 64 + n];
    }
    arena[i] = f2bf(val);
}

// fused biases: qkv0b[384] then qkv1b[4*384]
__global__ void bias_k(const float* __restrict__ q0b, const float* __restrict__ k0b,
                       const float* __restrict__ v0b,
                       const float* __restrict__ q1b, const float* __restrict__ k1b,
                       const float* __restrict__ v1b, float* __restrict__ out) {
    int i = blockIdx.x * 256 + threadIdx.x;
    if (i >= 1920) return;
    if (i < 384) {
        int sec = i >> 7, c = i & 127;
        out[i] = (sec == 0) ? q0b[c] : (sec == 1) ? k0b[c] : v0b[c];
    } else {
        int j = i - 384;
        int p = j / 384, rr = j - p * 384;
        int sec = rr >> 7, c = p * 128 + (rr & 127);
        out[i] = (sec == 0) ? q1b[c] : (sec == 1) ? k1b[c] : v1b[c];
    }
}

// ---------------- f32 -> bf16 convert (8 elems/thread) ----------------
__global__ void cvt_k(const float* __restrict__ in, u16* __restrict__ out, int n8) {
    int i = blockIdx.x * 256 + threadIdx.x;
    if (i >= n8) return;
    float4 a = *(const float4*)(in + (size_t)i * 8);
    float4 b = *(const float4*)(in + (size_t)i * 8 + 4);
    ushort8 o = {f2bf(a.x), f2bf(a.y), f2bf(a.z), f2bf(a.w),
                 f2bf(b.x), f2bf(b.y), f2bf(b.z), f2bf(b.w)};
    *(ushort8*)(out + (size_t)i * 8) = o;
}

// ---------------- MFMA GEMM v2: C[M,N] = A[M,K](bf16) @ Bt[N,K](bf16)^T + bias ----------
// BM=128 x BN=128 per block (grid.y = N/128 tiles); full K staged in STATIC LDS
// (one barrier per 128-K chunk); 256 thr = 4 waves (2x2 of 64x64).
template <bool OUTBF16, int K>
__global__ __launch_bounds__(256) void mgemm2(const u16* __restrict__ A,
                                              const u16* __restrict__ Bt,
                                              const float* __restrict__ bias,
                                              void* __restrict__ C,
                                              int M, int N, int ldc) {
    const int LDK = 136;                 // 128 + 8 u16 pad: 16B-aligned rows, 2-way bank max
    __shared__ __align__(16) u16 As[128][LDK];   // 34,816 B
    __shared__ __align__(16) u16 Bs[128][LDK];   // 34,816 B (69,632 total, static)
    const int bm = blockIdx.x * 128;
    const int bn = blockIdx.y * 128;
    const int t = threadIdx.x, lane = t & 63, wid = t >> 6;
    const int wm = (wid >> 1) * 64, wn = (wid & 1) * 64;
    f32x4 acc[4][4] = {};
    for (int k0 = 0; k0 < K; k0 += 128) {
#pragma unroll
        for (int c = 0; c < 8; ++c) {    // stage 128x128 A and Bt chunks
            int ch = c * 256 + t;        // 0..2047; row = ch/16, 16B chunk = ch%16
            int r = ch >> 4, off = (ch & 15) * 8;
            short8v av = {};
            if (bm + r < M) av = *(const short8v*)(A + (size_t)(bm + r) * K + k0 + off);
            *(short8v*)(&As[r][off]) = av;
            short8v bv = {};
            if (bn + r < N) bv = *(const short8v*)(Bt + (size_t)(bn + r) * K + k0 + off);
            *(short8v*)(&Bs[r][off]) = bv;
        }
        __syncthreads();
#pragma unroll
        for (int ks = 0; ks < 4; ++ks) {
            int kr = ks * 32 + (lane >> 4) * 8;
            short8v af[4], bfr[4];
#pragma unroll
            for (int i = 0; i < 4; ++i) {
                af[i]  = *(const short8v*)(&As[wm + i * 16 + (lane & 15)][kr]);
                bfr[i] = *(const short8v*)(&Bs[wn + i * 16 + (lane & 15)][kr]);
            }
#pragma unroll
            for (int mi = 0; mi < 4; ++mi)
#pragma unroll
                for (int ni = 0; ni < 4; ++ni)
                    acc[mi][ni] = __builtin_amdgcn_mfma_f32_16x16x32_bf16(
                        af[mi], bfr[ni], acc[mi][ni], 0, 0, 0);
        }
        if (k0 + 128 < K) __syncthreads();
    }
    // epilogue: C/D frag layout col=lane&15, row=(lane>>4)*4+j
#pragma unroll
    for (int ni = 0; ni < 4; ++ni) {
        int ccol = bn + wn + ni * 16 + (lane & 15);
        if (ccol >= N) continue;
        float bs = bias[ccol];
#pragma unroll
        for (int mi = 0; mi < 4; ++mi) {
#pragma unroll
            for (int j = 0; j < 4; ++j) {
                int crow = bm + wm + mi * 16 + (lane >> 4) * 4 + j;
                if (crow >= M) continue;
                float val = acc[mi][ni][j] + bs;
                if (OUTBF16) ((u16*)C)[(size_t)crow * ldc + ccol] = f2bf(val);
                else         ((float*)C)[(size_t)crow * ldc + ccol] = val;
            }
        }
    }
}

// ---------------- CSR build ----------------
__global__ void zero2_k(int* __restrict__ a, int* __restrict__ b, int n) {
    int i = blockIdx.x * 256 + threadIdx.x;
    if (i < n) { a[i] = 0; b[i] = 0; }
}

__global__ void hist_k(const int* __restrict__ dst, int* __restrict__ cnt, int E) {
    int i = blockIdx.x * 256 + threadIdx.x;
    if (i < E) atomicAdd(&cnt[dst[i]], 1);
}

__global__ void blocksum_k(const int* __restrict__ cnt, int* __restrict__ bsum, int n) {
    __shared__ int sd[256];
    int i = blockIdx.x * 256 + threadIdx.x;
    sd[threadIdx.x] = (i < n) ? cnt[i] : 0;
    __syncthreads();
    for (int off = 128; off > 0; off >>= 1) {
        if (threadIdx.x < off) sd[threadIdx.x] += sd[threadIdx.x + off];
        __syncthreads();
    }
    if (threadIdx.x == 0) bsum[blockIdx.x] = sd[0];
}

__global__ void scanb_k(int* bsum, int nb) {
    __shared__ int tmp[512];
    int t = threadIdx.x;
    tmp[t] = (t < nb) ? bsum[t] : 0;
    __syncthreads();
    for (int off = 1; off < 512; off <<= 1) {
        int v = (t >= off) ? tmp[t - off] : 0;
        __syncthreads();
        tmp[t] += v;
        __syncthreads();
    }
    if (t < nb) bsum[t] = (t ? tmp[t - 1] : 0);
}

__global__ void scanc_k(const int* __restrict__ cnt, const int* __restrict__ bsum,
                        int* __restrict__ row_off, int n, int E) {
    __shared__ int tmp[256];
    int b = blockIdx.x, t = threadIdx.x;
    int i = b * 256 + t;
    int own = (i < n) ? cnt[i] : 0;
    tmp[t] = own;
    __syncthreads();
    for (int off = 1; off < 256; off <<= 1) {
        int v = (t >= off) ? tmp[t - off] : 0;
        __syncthreads();
        tmp[t] += v;
        __syncthreads();
    }
    if (i < n) row_off[i] = bsum[b] + tmp[t] - own;
    if (b == 0 && t == 0) row_off[n] = E;
}

__global__ void scatter_k(const int* __restrict__ src, const int* __restrict__ dst,
                          const int* __restrict__ row_off, int* __restrict__ cur,
                          int* __restrict__ csr_src, int E) {
    int i = blockIdx.x * 256 + threadIdx.x;
    if (i < E) {
        int d = dst[i];
        int pos = row_off[d] + atomicAdd(&cur[d], 1);
        csr_src[pos] = src[i];
    }
}

// ---------------- attention layer 0: 8 heads x d=16, F=128, concat ----------------
// q/k/v at row stride 384 (fused buffer). lane l: feats 2l,2l+1; 8-lane reduce. Unroll 4.
__global__ __launch_bounds__(256) void attn0_k(const u16* __restrict__ q, const u16* __restrict__ k,
                                               const u16* __restrict__ v,
                                               const int* __restrict__ row_off,
                                               const int* __restrict__ csr,
                                               float* __restrict__ out, int n) {
    int w = (blockIdx.x * 256 + threadIdx.x) >> 6;
    int lane = threadIdx.x & 63;
    if (w >= n) return;
    int beg = row_off[w], end = row_off[w + 1];
    unsigned kv = *(const unsigned*)(k + (size_t)w * 384 + 2 * lane);
    float k0f = bf2f((u16)kv) * 0.25f, k1f = bf2f((u16)(kv >> 16)) * 0.25f;  // fold 1/sqrt(16)
    float den = 0.f, num0 = 0.f, num1 = 0.f;
    int e = beg;
    for (; e + 4 <= end; e += 4) {
        int s0 = csr[e], s1 = csr[e + 1], s2 = csr[e + 2], s3 = csr[e + 3];
        unsigned qa = *(const unsigned*)(q + (size_t)s0 * 384 + 2 * lane);
        unsigned qb = *(const unsigned*)(q + (size_t)s1 * 384 + 2 * lane);
        unsigned qc = *(const unsigned*)(q + (size_t)s2 * 384 + 2 * lane);
        unsigned qd = *(const unsigned*)(q + (size_t)s3 * 384 + 2 * lane);
        unsigned va = *(const unsigned*)(v + (size_t)s0 * 384 + 2 * lane);
        unsigned vb = *(const unsigned*)(v + (size_t)s1 * 384 + 2 * lane);
        unsigned vc = *(const unsigned*)(v + (size_t)s2 * 384 + 2 * lane);
        unsigned vd = *(const unsigned*)(v + (size_t)s3 * 384 + 2 * lane);
        float pa = bf2f((u16)qa) * k0f + bf2f((u16)(qa >> 16)) * k1f;
        float pb = bf2f((u16)qb) * k0f + bf2f((u16)(qb >> 16)) * k1f;
        float pc = bf2f((u16)qc) * k0f + bf2f((u16)(qc >> 16)) * k1f;
        float pd = bf2f((u16)qd) * k0f + bf2f((u16)(qd >> 16)) * k1f;
#pragma unroll
        for (int off = 1; off < 8; off <<= 1) {
            pa += __shfl_xor(pa, off); pb += __shfl_xor(pb, off);
            pc += __shfl_xor(pc, off); pd += __shfl_xor(pd, off);
        }
        float wa = __expf(pa), wb = __expf(pb);
        float wc = __expf(pc), wd = __expf(pd);
        den += (wa + wb) + (wc + wd);
        num0 = fmaf(wa, bf2f((u16)va), num0);
        num1 = fmaf(wa, bf2f((u16)(va >> 16)), num1);
        num0 = fmaf(wb, bf2f((u16)vb), num0);
        num1 = fmaf(wb, bf2f((u16)(vb >> 16)), num1);
        num0 = fmaf(wc, bf2f((u16)vc), num0);
        num1 = fmaf(wc, bf2f((u16)(vc >> 16)), num1);
        num0 = fmaf(wd, bf2f((u16)vd), num0);
        num1 = fmaf(wd, bf2f((u16)(vd >> 16)), num1);
    }
    for (; e < end; ++e) {
        int s = csr[e];
        unsigned qv = *(const unsigned*)(q + (size_t)s * 384 + 2 * lane);
        float p = bf2f((u16)qv) * k0f + bf2f((u16)(qv >> 16)) * k1f;
        p += __shfl_xor(p, 1);
        p += __shfl_xor(p, 2);
        p += __shfl_xor(p, 4);
        float wt = __expf(p);
        den += wt;
        unsigned vv = *(const unsigned*)(v + (size_t)s * 384 + 2 * lane);
        num0 = fmaf(wt, bf2f((u16)vv), num0);
        num1 = fmaf(wt, bf2f((u16)(vv >> 16)), num1);
    }
    float inv = (end > beg) ? 1.f / den : 0.f;
    *(float2*)(out + ((size_t)w << 7) + 2 * lane) = make_float2(num0 * inv, num1 * inv);
}

// ---------------- attention layer 1 (one 2-head pass): d=64, accumulate mean ----------------
template <bool FIRST>
__global__ __launch_bounds__(256) void attn1_k(const u16* __restrict__ q, const u16* __restrict__ k,
                                               const u16* __restrict__ v,
                                               const int* __restrict__ row_off,
                                               const int* __restrict__ csr,
                                               float* __restrict__ out, int n) {
    int w = (blockIdx.x * 256 + threadIdx.x) >> 6;
    int lane = threadIdx.x & 63;
    if (w >= n) return;
    int beg = row_off[w], end = row_off[w + 1];
    unsigned kv = *(const unsigned*)(k + (size_t)w * 384 + 2 * lane);
    float k0f = bf2f((u16)kv) * 0.125f, k1f = bf2f((u16)(kv >> 16)) * 0.125f;  // fold 1/sqrt(64)
    float den = 0.f, num0 = 0.f, num1 = 0.f;
    int e = beg;
    for (; e + 4 <= end; e += 4) {
        int s0 = csr[e], s1 = csr[e + 1], s2 = csr[e + 2], s3 = csr[e + 3];
        unsigned qa = *(const unsigned*)(q + (size_t)s0 * 384 + 2 * lane);
        unsigned qb = *(const unsigned*)(q + (size_t)s1 * 384 + 2 * lane);
        unsigned qc = *(const unsigned*)(q + (size_t)s2 * 384 + 2 * lane);
        unsigned qd = *(const unsigned*)(q + (size_t)s3 * 384 + 2 * lane);
        unsigned va = *(const unsigned*)(v + (size_t)s0 * 384 + 2 * lane);
        unsigned vb = *(const unsigned*)(v + (size_t)s1 * 384 + 2 * lane);
        unsigned vc = *(const unsigned*)(v + (size_t)s2 * 384 + 2 * lane);
        unsigned vd = *(const unsigned*)(v + (size_t)s3 * 384 + 2 * lane);
        float pa = bf2f((u16)qa) * k0f + bf2f((u16)(qa >> 16)) * k1f;
        float pb = bf2f((u16)qb) * k0f + bf2f((u16)(qb >> 16)) * k1f;
        float pc = bf2f((u16)qc) * k0f + bf2f((u16)(qc >> 16)) * k1f;
        float pd = bf2f((u16)qd) * k0f + bf2f((u16)(qd >> 16)) * k1f;
#pragma unroll
        for (int off = 1; off < 32; off <<= 1) {
            pa += __shfl_xor(pa, off); pb += __shfl_xor(pb, off);
            pc += __shfl_xor(pc, off); pd += __shfl_xor(pd, off);
        }
        float wa = __expf(pa), wb = __expf(pb);
        float wc = __expf(pc), wd = __expf(pd);
        den += (wa + wb) + (wc + wd);
        num0 = fmaf(wa, bf2f((u16)va), num0);
        num1 = fmaf(wa, bf2f((u16)(va >> 16)), num1);
        num0 = fmaf(wb, bf2f((u16)vb), num0);
        num1 = fmaf(wb, bf2f((u16)(vb >> 16)), num1);
        num0 = fmaf(wc, bf2f((u16)vc), num0);
        num1 = fmaf(wc, bf2f((u16)(vc >> 16)), num1);
        num0 = fmaf(wd, bf2f((u16)vd), num0);
        num1 = fmaf(wd, bf2f((u16)(vd >> 16)), num1);
    }
    for (; e < end; ++e) {
        int s = csr[e];
        unsigned qv = *(const unsigned*)(q + (size_t)s * 384 + 2 * lane);
        float p = bf2f((u16)qv) * k0f + bf2f((u16)(qv >> 16)) * k1f;
#pragma unroll
        for (int off = 1; off < 32; off <<= 1) p += __shfl_xor(p, off);
        float wt = __expf(p);
        den += wt;
        unsigned vv = *(const unsigned*)(v + (size_t)s * 384 + 2 * lane);
        num0 = fmaf(wt, bf2f((u16)vv), num0);
        num1 = fmaf(wt, bf2f((u16)(vv >> 16)), num1);
    }
    float inv = (end > beg) ? 1.f / den : 0.f;
    float o0 = num0 * inv, o1 = num1 * inv;
    o0 += __shfl_xor(o0, 32);   // combine the two heads (same output dim)
    o1 += __shfl_xor(o1, 32);
    if (lane < 32) {
        float2* op = (float2*)(out + ((size_t)w << 6) + 2 * lane);
        if (FIRST) {
            *op = make_float2(o0 * 0.125f, o1 * 0.125f);
        } else {
            float2 tv = *op;
            tv.x += o0 * 0.125f; tv.y += o1 * 0.125f;
            *op = tv;
        }
    }
}

// ---------------- gated residual + LN + relu (layer 0), bf16 h1 out ----------------
__global__ __launch_bounds__(256) void gres0_k(const float* __restrict__ x, const float* __restrict__ res,
                                               const float* __restrict__ gw,
                                               const float* __restrict__ lng, const float* __restrict__ lnb,
                                               u16* __restrict__ h1, int n) {
    int w = (blockIdx.x * 256 + threadIdx.x) >> 6;
    int lane = threadIdx.x & 63;
    if (w >= n) return;
    size_t base = (size_t)w * 128;
    float x1 = x[base + lane], x2 = x[base + lane + 64];
    float r1 = res[base + lane], r2 = res[base + lane + 64];
    float ca1 = gw[lane] + gw[256 + lane];
    float ca2 = gw[lane + 64] + gw[256 + lane + 64];
    float cr1 = gw[128 + lane] - gw[256 + lane];
    float cr2 = gw[128 + lane + 64] - gw[256 + lane + 64];
    float dot = x1 * ca1 + x2 * ca2 + r1 * cr1 + r2 * cr2;
#pragma unroll
    for (int off = 1; off < 64; off <<= 1) dot += __shfl_xor(dot, off);
    float g = 1.f / (1.f + __expf(-dot));
    float o1 = x1 * g + r1 * (1.f - g);
    float o2 = x2 * g + r2 * (1.f - g);
    float s = o1 + o2;
#pragma unroll
    for (int off = 1; off < 64; off <<= 1) s += __shfl_xor(s, off);
    float mu = s * (1.f / 128.f);
    float d1 = o1 - mu, d2 = o2 - mu;
    float vs = d1 * d1 + d2 * d2;
#pragma unroll
    for (int off = 1; off < 64; off <<= 1) vs += __shfl_xor(vs, off);
    float rstd = rsqrtf(vs * (1.f / 128.f) + 1e-5f);
    float y1 = d1 * rstd * lng[lane] + lnb[lane];
    float y2 = d2 * rstd * lng[lane + 64] + lnb[lane + 64];
    h1[base + lane] = f2bf(fmaxf(y1, 0.f));
    h1[base + lane + 64] = f2bf(fmaxf(y2, 0.f));
}

// ---------------- gated residual only (layer 1, d=64) ----------------
__global__ __launch_bounds__(256) void gres1_k(const float* __restrict__ x, const float* __restrict__ res,
                                               const float* __restrict__ gw,
                                               float* __restrict__ out, int n) {
    int w = (blockIdx.x * 256 + threadIdx.x) >> 6;
    int lane = threadIdx.x & 63;
    if (w >= n) return;
    size_t base = (size_t)w * 64;
    float xv = x[base + lane];
    float rv = res[base + lane];
    float ca = gw[lane] + gw[128 + lane];
    float cr = gw[64 + lane] - gw[128 + lane];
    float dot = xv * ca + rv * cr;
#pragma unroll
    for (int off = 1; off < 64; off <<= 1) dot += __shfl_xor(dot, off);
    float g = 1.f / (1.f + __expf(-dot));
    out[base + lane] = xv * g + rv * (1.f - g);
}

extern "C" void kernel_launch(void* const* d_in, const int* in_sizes, int n_in,
                              void* d_out, int out_size, void* d_ws, size_t ws_size,
                              hipStream_t stream) {
    const float* x    = (const float*)d_in[0];
    const int*   src  = (const int*)d_in[1];
    const int*   dst  = (const int*)d_in[2];
    const float* in_W = (const float*)d_in[3];
    const float* in_b = (const float*)d_in[4];
    const float* q0W = (const float*)d_in[5];  const float* q0b = (const float*)d_in[6];
    const float* k0W = (const float*)d_in[7];  const float* k0b = (const float*)d_in[8];
    const float* v0W = (const float*)d_in[9];  const float* v0b = (const float*)d_in[10];
    const float* r0W = (const float*)d_in[11]; const float* r0b = (const float*)d_in[12];
    const float* g0W = (const float*)d_in[13];
    const float* ln0g = (const float*)d_in[14]; const float* ln0b = (const float*)d_in[15];
    const float* q1W = (const float*)d_in[16]; const float* q1b = (const float*)d_in[17];
    const float* k1W = (const float*)d_in[18]; const float* k1b = (const float*)d_in[19];
    const float* v1W = (const float*)d_in[20]; const float* v1b = (const float*)d_in[21];
    const float* r1W = (const float*)d_in[22]; const float* r1b = (const float*)d_in[23];
    const float* g1W = (const float*)d_in[24];

    const int N = in_sizes[0] / 256;   // 100000
    const int E = in_sizes[1];         // 1600000
    (void)ws_size; (void)n_in; (void)out_size;

    // ---- workspace layout with reuse: peak ~186 MB ----
    auto rnd = [](size_t b) { return (b + 255) & ~(size_t)255; };
    char* base = (char*)d_ws;
    const size_t S_bf = rnd((size_t)N * 128 * 2);   // 25.6 MB
    const size_t S_f  = rnd((size_t)N * 128 * 4);   // 51.2 MB
    size_t o = 0;
    int* row_off = (int*)(base + o); o += rnd(((size_t)N + 1) * 4);
    int* csr     = (int*)(base + o); o += rnd((size_t)E * 4);
    u16* warena  = (u16*)(base + o); o += rnd((size_t)303104 * 2);
    float* barena = (float*)(base + o); o += rnd((size_t)1920 * 4);
    const size_t R0 = o;                 // 51.2: cnt/cur/bsum -> h -> a0 -> {res1o, a1}
    const size_t R1 = R0 + S_f;          // 76.8: x_bf -> QKV0 -> h1 (+ PASS tail)
    const size_t R2 = R1 + 3 * S_bf;     // 51.2: res0o -> (PASS tail)
    int* cnt  = (int*)(base + R0);
    int* cur  = (int*)(base + R0 + rnd((size_t)N * 4));
    int* bsum = (int*)(base + R0 + 2 * rnd((size_t)N * 4));
    u16*   h     = (u16*)(base + R0);
    float* a0    = (float*)(base + R0);
    float* res1o = (float*)(base + R0);
    float* a1    = (float*)(base + R0 + rnd((size_t)N * 64 * 4));
    u16* x_bf = (u16*)(base + R1);                 // N x 256 bf16, dies after in-GEMM
    u16* QKV0 = (u16*)(base + R1);                 // N x 384 bf16 (overlays x_bf)
    u16* h1   = (u16*)(base + R1);                 // N x 128 bf16 (overlays QKV0, dead after attn0)
    u16* PASS = (u16*)(base + R1 + S_bf);          // N x 384 bf16, spans R1 slots 1-2 + R2 head
    float* res0o = (float*)(base + R2);            // dead after gres0 (before PASS written)

    // weight arena sections
    u16* inWt  = warena;
    u16* qkv0t = warena + 32768;
    u16* r0t   = warena + 81920;
    u16* qkv1t = warena + 98304;
    u16* r1t   = warena + 294912;
    float* qkv0b = barena;
    float* qkv1b = barena + 384;

    dim3 blk(256);
    int nwb = (N * 64 + 255) / 256;   // one wave per node
    int nb  = (N + 255) / 256;        // 391 (<= 512)
    int mb  = (N + 127) / 128;        // 782

    // ---- prep (weights/bias/x convert) ----
    prep_k<<<(303104 + 255) / 256, blk, 0, stream>>>(in_W, q0W, k0W, v0W, r0W,
                                                     q1W, k1W, v1W, r1W, warena);
    bias_k<<<8, blk, 0, stream>>>(q0b, k0b, v0b, q1b, k1b, v1b, barena);
    cvt_k<<<(N * 32 + 255) / 256, blk, 0, stream>>>(x, x_bf, N * 32);

    // ---- CSR build ----
    zero2_k<<<nb, blk, 0, stream>>>(cnt, cur, N);
    hist_k<<<(E + 255) / 256, blk, 0, stream>>>(dst, cnt, E);
    blocksum_k<<<nb, blk, 0, stream>>>(cnt, bsum, N);
    scanb_k<<<1, 512, 0, stream>>>(bsum, nb);
    scanc_k<<<nb, blk, 0, stream>>>(cnt, bsum, row_off, N, E);
    scatter_k<<<(E + 255) / 256, blk, 0, stream>>>(src, dst, row_off, cur, csr, E);

    // ---- layer 0 ----
    mgemm2<true, 256><<<dim3(mb, 1), blk, 0, stream>>>(x_bf, inWt, in_b, h, N, 128, 128);
    mgemm2<true, 128><<<dim3(mb, 3), blk, 0, stream>>>(h, qkv0t, qkv0b, QKV0, N, 384, 384);
    mgemm2<false, 128><<<dim3(mb, 1), blk, 0, stream>>>(h, r0t, r0b, res0o, N, 128, 128);

    attn0_k<<<nwb, blk, 0, stream>>>(QKV0, QKV0 + 128, QKV0 + 256, row_off, csr, a0, N);
    gres0_k<<<nwb, blk, 0, stream>>>(a0, res0o, g0W, ln0g, ln0b, h1, N);

    // ---- layer 1: res path, then 4 passes of 2 heads each ----
    mgemm2<false, 128><<<dim3(mb, 1), blk, 0, stream>>>(h1, r1t, r1b, res1o, N, 64, 64);

    for (int p = 0; p < 4; ++p) {
        mgemm2<true, 128><<<dim3(mb, 3), blk, 0, stream>>>(
            h1, qkv1t + (size_t)p * 384 * 128, qkv1b + p * 384, PASS, N, 384, 384);
        if (p == 0) attn1_k<true><<<nwb, blk, 0, stream>>>(PASS, PASS + 128, PASS + 256,
                                                           row_off, csr, a1, N);
        else        attn1_k<false><<<nwb, blk, 0, stream>>>(PASS, PASS + 128, PASS + 256,
                                                            row_off, csr, a1, N);
    }

    gres1_k<<<nwb, blk, 0, stream>>>(a1, res1o, g1W, (float*)d_out, N);
}

// Round 6
// 1222.413 us; speedup vs baseline: 1.8327x; 1.0619x over previous
//
#include <hip/hip_runtime.h>

// GraphTransformerModel: 2-layer graph attention network.
// CSR build -> bf16 MFMA GEMMs (global_load_lds + XOR-swizzled LDS, BK=64)
// -> attn0 -> gres0+LN -> per-2-head passes {fused qkv1 GEMM -> attn1} -> gres1.
// q/k/v live in fused [N][384] bf16 buffers; all accumulation f32.
// Peak workspace ~186 MB.

typedef unsigned short u16;
typedef __attribute__((ext_vector_type(8))) unsigned short ushort8;
typedef __attribute__((ext_vector_type(8))) short short8v;   // 8 bf16 (4 VGPRs)
typedef __attribute__((ext_vector_type(4))) float f32x4;

__device__ __forceinline__ float bf2f(unsigned short u) {
    return __uint_as_float(((unsigned)u) << 16);
}
__device__ __forceinline__ unsigned short f2bf(float f) {
    unsigned u = __float_as_uint(f);
    unsigned r = 0x7fffu + ((u >> 16) & 1u);   // round-to-nearest-even
    return (unsigned short)((u + r) >> 16);
}

// async global->LDS, 16B per lane; dest is wave-uniform base + lane*16 (HW).
__device__ __forceinline__ void gload16(const void* gp, const void* lp) {
    __builtin_amdgcn_global_load_lds(
        (const __attribute__((address_space(1))) unsigned*)(uintptr_t)gp,
        (__attribute__((address_space(3))) unsigned*)(unsigned)(uintptr_t)lp,
        16, 0, 0);
}

// ---------------- fused weight prep: all transposed bf16 weights in one kernel ----------------
// arena (u16): [0)=inWt[128][256]  [32768)=qkv0t[384][128]  [81920)=r0t[128][128]
//              [98304)=qkv1t[4][384][128]  [294912)=r1t[64][128]  total 303104
__global__ void prep_k(const float* __restrict__ inW,
                       const float* __restrict__ q0W, const float* __restrict__ k0W,
                       const float* __restrict__ v0W, const float* __restrict__ r0W,
                       const float* __restrict__ q1W, const float* __restrict__ k1W,
                       const float* __restrict__ v1W, const float* __restrict__ r1W,
                       u16* __restrict__ arena) {
    int i = blockIdx.x * 256 + threadIdx.x;
    if (i >= 303104) return;
    float val;
    if (i < 32768) {                       // inWt[n][k] = inW[k][n], K=256, N=128
        int n = i >> 8, k = i & 255;
        val = inW[k * 128 + n];
    } else if (i < 81920) {                // qkv0t
        int j = i - 32768;
        int r = j >> 7, kk = j & 127;
        int sec = r >> 7, c = r & 127;
        const float* s = (sec == 0) ? q0W : (sec == 1) ? k0W : v0W;
        val = s[kk * 128 + c];
    } else if (i < 98304) {                // r0t
        int j = i - 81920;
        int r = j >> 7, kk = j & 127;
        val = r0W[kk * 128 + r];
    } else if (i < 294912) {               // qkv1t[p][384][128]
        int j = i - 98304;
        int row = j >> 7, kk = j & 127;
        int p = row / 384, rr = row - p * 384;
        int sec = rr >> 7, c = p * 128 + (rr & 127);
        const float* s = (sec == 0) ? q1W : (sec == 1) ? k1W : v1W;
        val = s[kk * 512 + c];
    } else {                               // r1t[64][128]
        int j = i - 294912;
        int n = j >> 7, kk = j & 127;
        val = r1W[kk * 64 + n];
    }
    arena[i] = f2bf(val);
}

// fused biases: qkv0b[384] then qkv1b[4*384]
__global__ void bias_k(const float* __restrict__ q0b, const float* __restrict__ k0b,
                       const float* __restrict__ v0b,
                       const float* __restrict__ q1b, const float* __restrict__ k1b,
                       const float* __restrict__ v1b, float* __restrict__ out) {
    int i = blockIdx.x * 256 + threadIdx.x;
    if (i >= 1920) return;
    if (i < 384) {
        int sec = i >> 7, c = i & 127;
        out[i] = (sec == 0) ? q0b[c] : (sec == 1) ? k0b[c] : v0b[c];
    } else {
        int j = i - 384;
        int p = j / 384, rr = j - p * 384;
        int sec = rr >> 7, c = p * 128 + (rr & 127);
        out[i] = (sec == 0) ? q1b[c] : (sec == 1) ? k1b[c] : v1b[c];
    }
}

// ---------------- f32 -> bf16 convert (8 elems/thread) ----------------
__global__ void cvt_k(const float* __restrict__ in, u16* __restrict__ out, int n8) {
    int i = blockIdx.x * 256 + threadIdx.x;
    if (i >= n8) return;
    float4 a = *(const float4*)(in + (size_t)i * 8);
    float4 b = *(const float4*)(in + (size_t)i * 8 + 4);
    ushort8 o = {f2bf(a.x), f2bf(a.y), f2bf(a.z), f2bf(a.w),
                 f2bf(b.x), f2bf(b.y), f2bf(b.z), f2bf(b.w)};
    *(ushort8*)(out + (size_t)i * 8) = o;
}

// ---------------- MFMA GEMM v3: C[M,N] = A[M,K](bf16) @ Bt[N,K](bf16)^T + bias ----------
// 128x128 tile, BK=64 chunks staged via global_load_lds into linear LDS with
// XOR swizzle (source column pre-permuted j^(row&7); ds_read applies same XOR).
// 256 thr = 4 waves (2x2 of 64x64); 32 KB LDS.
template <bool OUTBF16, int K>
__global__ __launch_bounds__(256) void mgemm3(const u16* __restrict__ A,
                                              const u16* __restrict__ Bt,
                                              const float* __restrict__ bias,
                                              void* __restrict__ C,
                                              int M, int Nvalid, int ldc) {
    __shared__ __align__(16) u16 As[128 * 64];   // 16 KB, rows of 128 B, linear
    __shared__ __align__(16) u16 Bs[128 * 64];   // 16 KB
    const int bm = blockIdx.x * 128;
    const int bn = blockIdx.y * 128;
    const int t = threadIdx.x, lane = t & 63, wid = t >> 6;
    const int wm = (wid >> 1) * 64, wn = (wid & 1) * 64;
    // staging geometry: wave-load = 8 rows x 64 cols = 1024 B; lane covers
    // (row = seg*8 + lane>>3, phys 16B chunk = lane&7) which must hold logical
    // chunk (lane&7)^(row&7) = (lane&7)^(lane>>3).
    const int jlog = ((lane & 7) ^ (lane >> 3)) * 8;   // element col within chunk row
    f32x4 acc[4][4] = {};
    for (int k0 = 0; k0 < K; k0 += 64) {
#pragma unroll
        for (int c2 = 0; c2 < 4; ++c2) {
            int seg = c2 * 4 + wid;               // 0..15, wave-uniform
            int row = seg * 8 + (lane >> 3);
            int ga = bm + row; if (ga >= M) ga = 0;           // clamped; epilogue guards
            gload16(A + (size_t)ga * K + k0 + jlog, (const char*)As + seg * 1024);
            int gb = bn + row; if (gb >= Nvalid) gb = 0;
            gload16(Bt + (size_t)gb * K + k0 + jlog, (const char*)Bs + seg * 1024);
        }
        __syncthreads();   // drains vmcnt (incl. global_load_lds) before reads
#pragma unroll
        for (int ks = 0; ks < 2; ++ks) {
            const int jx = ks * 4 + (lane >> 4);   // logical 16B chunk (elem col kr>>3)
            short8v af[4], bfr[4];
#pragma unroll
            for (int i = 0; i < 4; ++i) {
                int ra = wm + i * 16 + (lane & 15);
                af[i] = *(const short8v*)((const char*)As + ra * 128 + ((jx ^ (ra & 7)) << 4));
                int rb = wn + i * 16 + (lane & 15);
                bfr[i] = *(const short8v*)((const char*)Bs + rb * 128 + ((jx ^ (rb & 7)) << 4));
            }
#pragma unroll
            for (int mi = 0; mi < 4; ++mi)
#pragma unroll
                for (int ni = 0; ni < 4; ++ni)
                    acc[mi][ni] = __builtin_amdgcn_mfma_f32_16x16x32_bf16(
                        af[mi], bfr[ni], acc[mi][ni], 0, 0, 0);
        }
        if (k0 + 64 < K) __syncthreads();
    }
    // epilogue: C/D frag layout col=lane&15, row=(lane>>4)*4+j
#pragma unroll
    for (int ni = 0; ni < 4; ++ni) {
        int ccol = bn + wn + ni * 16 + (lane & 15);
        if (ccol >= Nvalid) continue;
        float bs = bias[ccol];
#pragma unroll
        for (int mi = 0; mi < 4; ++mi) {
#pragma unroll
            for (int j = 0; j < 4; ++j) {
                int crow = bm + wm + mi * 16 + (lane >> 4) * 4 + j;
                if (crow >= M) continue;
                float val = acc[mi][ni][j] + bs;
                if (OUTBF16) ((u16*)C)[(size_t)crow * ldc + ccol] = f2bf(val);
                else         ((float*)C)[(size_t)crow * ldc + ccol] = val;
            }
        }
    }
}

// ---------------- CSR build ----------------
__global__ void zero2_k(int* __restrict__ a, int* __restrict__ b, int n) {
    int i = blockIdx.x * 256 + threadIdx.x;
    if (i < n) { a[i] = 0; b[i] = 0; }
}

__global__ void hist_k(const int* __restrict__ dst, int* __restrict__ cnt, int E) {
    int i = blockIdx.x * 256 + threadIdx.x;
    if (i < E) atomicAdd(&cnt[dst[i]], 1);
}

__global__ void blocksum_k(const int* __restrict__ cnt, int* __restrict__ bsum, int n) {
    __shared__ int sd[256];
    int i = blockIdx.x * 256 + threadIdx.x;
    sd[threadIdx.x] = (i < n) ? cnt[i] : 0;
    __syncthreads();
    for (int off = 128; off > 0; off >>= 1) {
        if (threadIdx.x < off) sd[threadIdx.x] += sd[threadIdx.x + off];
        __syncthreads();
    }
    if (threadIdx.x == 0) bsum[blockIdx.x] = sd[0];
}

__global__ void scanb_k(int* bsum, int nb) {
    __shared__ int tmp[512];
    int t = threadIdx.x;
    tmp[t] = (t < nb) ? bsum[t] : 0;
    __syncthreads();
    for (int off = 1; off < 512; off <<= 1) {
        int v = (t >= off) ? tmp[t - off] : 0;
        __syncthreads();
        tmp[t] += v;
        __syncthreads();
    }
    if (t < nb) bsum[t] = (t ? tmp[t - 1] : 0);
}

__global__ void scanc_k(const int* __restrict__ cnt, const int* __restrict__ bsum,
                        int* __restrict__ row_off, int n, int E) {
    __shared__ int tmp[256];
    int b = blockIdx.x, t = threadIdx.x;
    int i = b * 256 + t;
    int own = (i < n) ? cnt[i] : 0;
    tmp[t] = own;
    __syncthreads();
    for (int off = 1; off < 256; off <<= 1) {
        int v = (t >= off) ? tmp[t - off] : 0;
        __syncthreads();
        tmp[t] += v;
        __syncthreads();
    }
    if (i < n) row_off[i] = bsum[b] + tmp[t] - own;
    if (b == 0 && t == 0) row_off[n] = E;
}

__global__ void scatter_k(const int* __restrict__ src, const int* __restrict__ dst,
                          const int* __restrict__ row_off, int* __restrict__ cur,
                          int* __restrict__ csr_src, int E) {
    int i = blockIdx.x * 256 + threadIdx.x;
    if (i < E) {
        int d = dst[i];
        int pos = row_off[d] + atomicAdd(&cur[d], 1);
        csr_src[pos] = src[i];
    }
}

// ---------------- attention layer 0: 8 heads x d=16, F=128, concat ----------------
// q/k/v at row stride 384 (fused buffer). lane l: feats 2l,2l+1; 8-lane reduce. Unroll 4.
__global__ __launch_bounds__(256) void attn0_k(const u16* __restrict__ q, const u16* __restrict__ k,
                                               const u16* __restrict__ v,
                                               const int* __restrict__ row_off,
                                               const int* __restrict__ csr,
                                               float* __restrict__ out, int n) {
    int w = (blockIdx.x * 256 + threadIdx.x) >> 6;
    int lane = threadIdx.x & 63;
    if (w >= n) return;
    int beg = row_off[w], end = row_off[w + 1];
    unsigned kv = *(const unsigned*)(k + (size_t)w * 384 + 2 * lane);
    float k0f = bf2f((u16)kv) * 0.25f, k1f = bf2f((u16)(kv >> 16)) * 0.25f;  // fold 1/sqrt(16)
    float den = 0.f, num0 = 0.f, num1 = 0.f;
    int e = beg;
    for (; e + 4 <= end; e += 4) {
        int s0 = csr[e], s1 = csr[e + 1], s2 = csr[e + 2], s3 = csr[e + 3];
        unsigned qa = *(const unsigned*)(q + (size_t)s0 * 384 + 2 * lane);
        unsigned qb = *(const unsigned*)(q + (size_t)s1 * 384 + 2 * lane);
        unsigned qc = *(const unsigned*)(q + (size_t)s2 * 384 + 2 * lane);
        unsigned qd = *(const unsigned*)(q + (size_t)s3 * 384 + 2 * lane);
        unsigned va = *(const unsigned*)(v + (size_t)s0 * 384 + 2 * lane);
        unsigned vb = *(const unsigned*)(v + (size_t)s1 * 384 + 2 * lane);
        unsigned vc = *(const unsigned*)(v + (size_t)s2 * 384 + 2 * lane);
        unsigned vd = *(const unsigned*)(v + (size_t)s3 * 384 + 2 * lane);
        float pa = bf2f((u16)qa) * k0f + bf2f((u16)(qa >> 16)) * k1f;
        float pb = bf2f((u16)qb) * k0f + bf2f((u16)(qb >> 16)) * k1f;
        float pc = bf2f((u16)qc) * k0f + bf2f((u16)(qc >> 16)) * k1f;
        float pd = bf2f((u16)qd) * k0f + bf2f((u16)(qd >> 16)) * k1f;
#pragma unroll
        for (int off = 1; off < 8; off <<= 1) {
            pa += __shfl_xor(pa, off); pb += __shfl_xor(pb, off);
            pc += __shfl_xor(pc, off); pd += __shfl_xor(pd, off);
        }
        float wa = __expf(pa), wb = __expf(pb);
        float wc = __expf(pc), wd = __expf(pd);
        den += (wa + wb) + (wc + wd);
        num0 = fmaf(wa, bf2f((u16)va), num0);
        num1 = fmaf(wa, bf2f((u16)(va >> 16)), num1);
        num0 = fmaf(wb, bf2f((u16)vb), num0);
        num1 = fmaf(wb, bf2f((u16)(vb >> 16)), num1);
        num0 = fmaf(wc, bf2f((u16)vc), num0);
        num1 = fmaf(wc, bf2f((u16)(vc >> 16)), num1);
        num0 = fmaf(wd, bf2f((u16)vd), num0);
        num1 = fmaf(wd, bf2f((u16)(vd >> 16)), num1);
    }
    for (; e < end; ++e) {
        int s = csr[e];
        unsigned qv = *(const unsigned*)(q + (size_t)s * 384 + 2 * lane);
        float p = bf2f((u16)qv) * k0f + bf2f((u16)(qv >> 16)) * k1f;
        p += __shfl_xor(p, 1);
        p += __shfl_xor(p, 2);
        p += __shfl_xor(p, 4);
        float wt = __expf(p);
        den += wt;
        unsigned vv = *(const unsigned*)(v + (size_t)s * 384 + 2 * lane);
        num0 = fmaf(wt, bf2f((u16)vv), num0);
        num1 = fmaf(wt, bf2f((u16)(vv >> 16)), num1);
    }
    float inv = (end > beg) ? 1.f / den : 0.f;
    *(float2*)(out + ((size_t)w << 7) + 2 * lane) = make_float2(num0 * inv, num1 * inv);
}

// ---------------- attention layer 1 (one 2-head pass): d=64, accumulate mean ----------------
template <bool FIRST>
__global__ __launch_bounds__(256) void attn1_k(const u16* __restrict__ q, const u16* __restrict__ k,
                                               const u16* __restrict__ v,
                                               const int* __restrict__ row_off,
                                               const int* __restrict__ csr,
                                               float* __restrict__ out, int n) {
    int w = (blockIdx.x * 256 + threadIdx.x) >> 6;
    int lane = threadIdx.x & 63;
    if (w >= n) return;
    int beg = row_off[w], end = row_off[w + 1];
    unsigned kv = *(const unsigned*)(k + (size_t)w * 384 + 2 * lane);
    float k0f = bf2f((u16)kv) * 0.125f, k1f = bf2f((u16)(kv >> 16)) * 0.125f;  // fold 1/sqrt(64)
    float den = 0.f, num0 = 0.f, num1 = 0.f;
    int e = beg;
    for (; e + 4 <= end; e += 4) {
        int s0 = csr[e], s1 = csr[e + 1], s2 = csr[e + 2], s3 = csr[e + 3];
        unsigned qa = *(const unsigned*)(q + (size_t)s0 * 384 + 2 * lane);
        unsigned qb = *(const unsigned*)(q + (size_t)s1 * 384 + 2 * lane);
        unsigned qc = *(const unsigned*)(q + (size_t)s2 * 384 + 2 * lane);
        unsigned qd = *(const unsigned*)(q + (size_t)s3 * 384 + 2 * lane);
        unsigned va = *(const unsigned*)(v + (size_t)s0 * 384 + 2 * lane);
        unsigned vb = *(const unsigned*)(v + (size_t)s1 * 384 + 2 * lane);
        unsigned vc = *(const unsigned*)(v + (size_t)s2 * 384 + 2 * lane);
        unsigned vd = *(const unsigned*)(v + (size_t)s3 * 384 + 2 * lane);
        float pa = bf2f((u16)qa) * k0f + bf2f((u16)(qa >> 16)) * k1f;
        float pb = bf2f((u16)qb) * k0f + bf2f((u16)(qb >> 16)) * k1f;
        float pc = bf2f((u16)qc) * k0f + bf2f((u16)(qc >> 16)) * k1f;
        float pd = bf2f((u16)qd) * k0f + bf2f((u16)(qd >> 16)) * k1f;
#pragma unroll
        for (int off = 1; off < 32; off <<= 1) {
            pa += __shfl_xor(pa, off); pb += __shfl_xor(pb, off);
            pc += __shfl_xor(pc, off); pd += __shfl_xor(pd, off);
        }
        float wa = __expf(pa), wb = __expf(pb);
        float wc = __expf(pc), wd = __expf(pd);
        den += (wa + wb) + (wc + wd);
        num0 = fmaf(wa, bf2f((u16)va), num0);
        num1 = fmaf(wa, bf2f((u16)(va >> 16)), num1);
        num0 = fmaf(wb, bf2f((u16)vb), num0);
        num1 = fmaf(wb, bf2f((u16)(vb >> 16)), num1);
        num0 = fmaf(wc, bf2f((u16)vc), num0);
        num1 = fmaf(wc, bf2f((u16)(vc >> 16)), num1);
        num0 = fmaf(wd, bf2f((u16)vd), num0);
        num1 = fmaf(wd, bf2f((u16)(vd >> 16)), num1);
    }
    for (; e < end; ++e) {
        int s = csr[e];
        unsigned qv = *(const unsigned*)(q + (size_t)s * 384 + 2 * lane);
        float p = bf2f((u16)qv) * k0f + bf2f((u16)(qv >> 16)) * k1f;
#pragma unroll
        for (int off = 1; off < 32; off <<= 1) p += __shfl_xor(p, off);
        float wt = __expf(p);
        den += wt;
        unsigned vv = *(const unsigned*)(v + (size_t)s * 384 + 2 * lane);
        num0 = fmaf(wt, bf2f((u16)vv), num0);
        num1 = fmaf(wt, bf2f((u16)(vv >> 16)), num1);
    }
    float inv = (end > beg) ? 1.f / den : 0.f;
    float o0 = num0 * inv, o1 = num1 * inv;
    o0 += __shfl_xor(o0, 32);   // combine the two heads (same output dim)
    o1 += __shfl_xor(o1, 32);
    if (lane < 32) {
        float2* op = (float2*)(out + ((size_t)w << 6) + 2 * lane);
        if (FIRST) {
            *op = make_float2(o0 * 0.125f, o1 * 0.125f);
        } else {
            float2 tv = *op;
            tv.x += o0 * 0.125f; tv.y += o1 * 0.125f;
            *op = tv;
        }
    }
}

// ---------------- gated residual + LN + relu (layer 0), bf16 h1 out ----------------
__global__ __launch_bounds__(256) void gres0_k(const float* __restrict__ x, const float* __restrict__ res,
                                               const float* __restrict__ gw,
                                               const float* __restrict__ lng, const float* __restrict__ lnb,
                                               u16* __restrict__ h1, int n) {
    int w = (blockIdx.x * 256 + threadIdx.x) >> 6;
    int lane = threadIdx.x & 63;
    if (w >= n) return;
    size_t base = (size_t)w * 128;
    float x1 = x[base + lane], x2 = x[base + lane + 64];
    float r1 = res[base + lane], r2 = res[base + lane + 64];
    float ca1 = gw[lane] + gw[256 + lane];
    float ca2 = gw[lane + 64] + gw[256 + lane + 64];
    float cr1 = gw[128 + lane] - gw[256 + lane];
    float cr2 = gw[128 + lane + 64] - gw[256 + lane + 64];
    float dot = x1 * ca1 + x2 * ca2 + r1 * cr1 + r2 * cr2;
#pragma unroll
    for (int off = 1; off < 64; off <<= 1) dot += __shfl_xor(dot, off);
    float g = 1.f / (1.f + __expf(-dot));
    float o1 = x1 * g + r1 * (1.f - g);
    float o2 = x2 * g + r2 * (1.f - g);
    float s = o1 + o2;
#pragma unroll
    for (int off = 1; off < 64; off <<= 1) s += __shfl_xor(s, off);
    float mu = s * (1.f / 128.f);
    float d1 = o1 - mu, d2 = o2 - mu;
    float vs = d1 * d1 + d2 * d2;
#pragma unroll
    for (int off = 1; off < 64; off <<= 1) vs += __shfl_xor(vs, off);
    float rstd = rsqrtf(vs * (1.f / 128.f) + 1e-5f);
    float y1 = d1 * rstd * lng[lane] + lnb[lane];
    float y2 = d2 * rstd * lng[lane + 64] + lnb[lane + 64];
    h1[base + lane] = f2bf(fmaxf(y1, 0.f));
    h1[base + lane + 64] = f2bf(fmaxf(y2, 0.f));
}

// ---------------- gated residual only (layer 1, d=64) ----------------
__global__ __launch_bounds__(256) void gres1_k(const float* __restrict__ x, const float* __restrict__ res,
                                               const float* __restrict__ gw,
                                               float* __restrict__ out, int n) {
    int w = (blockIdx.x * 256 + threadIdx.x) >> 6;
    int lane = threadIdx.x & 63;
    if (w >= n) return;
    size_t base = (size_t)w * 64;
    float xv = x[base + lane];
    float rv = res[base + lane];
    float ca = gw[lane] + gw[128 + lane];
    float cr = gw[64 + lane] - gw[128 + lane];
    float dot = xv * ca + rv * cr;
#pragma unroll
    for (int off = 1; off < 64; off <<= 1) dot += __shfl_xor(dot, off);
    float g = 1.f / (1.f + __expf(-dot));
    out[base + lane] = xv * g + rv * (1.f - g);
}

extern "C" void kernel_launch(void* const* d_in, const int* in_sizes, int n_in,
                              void* d_out, int out_size, void* d_ws, size_t ws_size,
                              hipStream_t stream) {
    const float* x    = (const float*)d_in[0];
    const int*   src  = (const int*)d_in[1];
    const int*   dst  = (const int*)d_in[2];
    const float* in_W = (const float*)d_in[3];
    const float* in_b = (const float*)d_in[4];
    const float* q0W = (const float*)d_in[5];  const float* q0b = (const float*)d_in[6];
    const float* k0W = (const float*)d_in[7];  const float* k0b = (const float*)d_in[8];
    const float* v0W = (const float*)d_in[9];  const float* v0b = (const float*)d_in[10];
    const float* r0W = (const float*)d_in[11]; const float* r0b = (const float*)d_in[12];
    const float* g0W = (const float*)d_in[13];
    const float* ln0g = (const float*)d_in[14]; const float* ln0b = (const float*)d_in[15];
    const float* q1W = (const float*)d_in[16]; const float* q1b = (const float*)d_in[17];
    const float* k1W = (const float*)d_in[18]; const float* k1b = (const float*)d_in[19];
    const float* v1W = (const float*)d_in[20]; const float* v1b = (const float*)d_in[21];
    const float* r1W = (const float*)d_in[22]; const float* r1b = (const float*)d_in[23];
    const float* g1W = (const float*)d_in[24];

    const int N = in_sizes[0] / 256;   // 100000
    const int E = in_sizes[1];         // 1600000
    (void)ws_size; (void)n_in; (void)out_size;

    // ---- workspace layout with reuse: peak ~186 MB ----
    auto rnd = [](size_t b) { return (b + 255) & ~(size_t)255; };
    char* base = (char*)d_ws;
    const size_t S_bf = rnd((size_t)N * 128 * 2);   // 25.6 MB
    const size_t S_f  = rnd((size_t)N * 128 * 4);   // 51.2 MB
    size_t o = 0;
    int* row_off = (int*)(base + o); o += rnd(((size_t)N + 1) * 4);
    int* csr     = (int*)(base + o); o += rnd((size_t)E * 4);
    u16* warena  = (u16*)(base + o); o += rnd((size_t)303104 * 2);
    float* barena = (float*)(base + o); o += rnd((size_t)1920 * 4);
    const size_t R0 = o;                 // 51.2: cnt/cur/bsum -> h -> a0 -> {res1o, a1}
    const size_t R1 = R0 + S_f;          // 76.8: x_bf -> QKV0 -> h1 (+ PASS tail)
    const size_t R2 = R1 + 3 * S_bf;     // 51.2: res0o -> (PASS tail)
    int* cnt  = (int*)(base + R0);
    int* cur  = (int*)(base + R0 + rnd((size_t)N * 4));
    int* bsum = (int*)(base + R0 + 2 * rnd((size_t)N * 4));
    u16*   h     = (u16*)(base + R0);
    float* a0    = (float*)(base + R0);
    float* res1o = (float*)(base + R0);
    float* a1    = (float*)(base + R0 + rnd((size_t)N * 64 * 4));
    u16* x_bf = (u16*)(base + R1);                 // N x 256 bf16, dies after in-GEMM
    u16* QKV0 = (u16*)(base + R1);                 // N x 384 bf16 (overlays x_bf)
    u16* h1   = (u16*)(base + R1);                 // N x 128 bf16 (overlays QKV0, dead after attn0)
    u16* PASS = (u16*)(base + R1 + S_bf);          // N x 384 bf16, spans R1 slots 1-2 + R2 head
    float* res0o = (float*)(base + R2);            // dead after gres0 (before PASS written)

    // weight arena sections
    u16* inWt  = warena;
    u16* qkv0t = warena + 32768;
    u16* r0t   = warena + 81920;
    u16* qkv1t = warena + 98304;
    u16* r1t   = warena + 294912;
    float* qkv0b = barena;
    float* qkv1b = barena + 384;

    dim3 blk(256);
    int nwb = (N * 64 + 255) / 256;   // one wave per node
    int nb  = (N + 255) / 256;        // 391 (<= 512)
    int mb  = (N + 127) / 128;        // 782

    // ---- prep (weights/bias/x convert) ----
    prep_k<<<(303104 + 255) / 256, blk, 0, stream>>>(in_W, q0W, k0W, v0W, r0W,
                                                     q1W, k1W, v1W, r1W, warena);
    bias_k<<<8, blk, 0, stream>>>(q0b, k0b, v0b, q1b, k1b, v1b, barena);
    cvt_k<<<(N * 32 + 255) / 256, blk, 0, stream>>>(x, x_bf, N * 32);

    // ---- CSR build ----
    zero2_k<<<nb, blk, 0, stream>>>(cnt, cur, N);
    hist_k<<<(E + 255) / 256, blk, 0, stream>>>(dst, cnt, E);
    blocksum_k<<<nb, blk, 0, stream>>>(cnt, bsum, N);
    scanb_k<<<1, 512, 0, stream>>>(bsum, nb);
    scanc_k<<<nb, blk, 0, stream>>>(cnt, bsum, row_off, N, E);
    scatter_k<<<(E + 255) / 256, blk, 0, stream>>>(src, dst, row_off, cur, csr, E);

    // ---- layer 0 ----
    mgemm3<true, 256><<<dim3(mb, 1), blk, 0, stream>>>(x_bf, inWt, in_b, h, N, 128, 128);
    mgemm3<true, 128><<<dim3(mb, 3), blk, 0, stream>>>(h, qkv0t, qkv0b, QKV0, N, 384, 384);
    mgemm3<false, 128><<<dim3(mb, 1), blk, 0, stream>>>(h, r0t, r0b, res0o, N, 128, 128);

    attn0_k<<<nwb, blk, 0, stream>>>(QKV0, QKV0 + 128, QKV0 + 256, row_off, csr, a0, N);
    gres0_k<<<nwb, blk, 0, stream>>>(a0, res0o, g0W, ln0g, ln0b, h1, N);

    // ---- layer 1: res path, then 4 passes of 2 heads each ----
    mgemm3<false, 128><<<dim3(mb, 1), blk, 0, stream>>>(h1, r1t, r1b, res1o, N, 64, 64);

    for (int p = 0; p < 4; ++p) {
        mgemm3<true, 128><<<dim3(mb, 3), blk, 0, stream>>>(
            h1, qkv1t + (size_t)p * 384 * 128, qkv1b + p * 384, PASS, N, 384, 384);
        if (p == 0) attn1_k<true><<<nwb, blk, 0, stream>>>(PASS, PASS + 128, PASS + 256,
                                                           row_off, csr, a1, N);
        else        attn1_k<false><<<nwb, blk, 0, stream>>>(PASS, PASS + 128, PASS + 256,
                                                            row_off, csr, a1, N);
    }

    gres1_k<<<nwb, blk, 0, stream>>>(a1, res1o, g1W, (float*)d_out, N);
}